// Round 7
// baseline (1153.225 us; speedup 1.0000x reference)
//
#include <hip/hip_runtime.h>

#define BS 100000
#define BQ 20000          // BS / 5
#define NWG 128           // workgroups in hist/fillA partition
#define CB  512           // nodes per coarse bucket
#define NCMAX 1024
#define CAP 12288         // LDS record capacity in fillA2B (mean 8192, sigma ~90)

typedef unsigned long long ull;

__device__ __forceinline__ float relu_(float v) { return fmaxf(v, 0.0f); }

// bf16 helpers (RNE pack, cheap unpack)
__device__ __forceinline__ unsigned bpack2(float a, float b) {
    unsigned ua = __float_as_uint(a), ub = __float_as_uint(b);
    ua = (ua + 0x7FFFu + ((ua >> 16) & 1u)) >> 16;
    ub = (ub + 0x7FFFu + ((ub >> 16) & 1u)) >> 16;
    return ua | (ub << 16);
}
__device__ __forceinline__ float blo(unsigned u) { return __uint_as_float(u << 16); }
__device__ __forceinline__ float bhi(unsigned u) { return __uint_as_float(u & 0xFFFF0000u); }

// ================= binning =================
// record: [dst&(CB-1):9 @51][src:19 @32][wbits:32 @0]
// csr rec: [src:19 @32][wbits:32 @0]  (node-sorted)

// per-WG coarse histogram
__global__ __launch_bounds__(256) void hist_kernel(
    const int* __restrict__ dst, int E, int NC, int* __restrict__ hist2D)
{
    __shared__ int lc[NCMAX];
    int t = threadIdx.x, g = blockIdx.x;
    for (int i = t; i < NC; i += 256) lc[i] = 0;
    __syncthreads();
    int per = (E + NWG - 1) / NWG;
    int lo = g * per, hi = min(lo + per, E);
    for (int i = lo + t; i < hi; i += 256) atomicAdd(&lc[dst[i] >> 9], 1);
    __syncthreads();
    for (int b = t; b < NC; b += 256) hist2D[b * NWG + g] = lc[b];
}

// single-block exclusive scan for large n (two reads of in[])
__global__ __launch_bounds__(1024) void scan_big_kernel(
    const int* __restrict__ in, int n, int* __restrict__ out)
{
    __shared__ int s[1024];
    int t = threadIdx.x;
    int chunk = (n + 1023) / 1024;
    int lo = t * chunk, hi = min(lo + chunk, n);
    int sum = 0;
    for (int i = lo; i < hi; i++) sum += in[i];
    s[t] = sum;
    __syncthreads();
    for (int d = 1; d < 1024; d <<= 1) {
        int x = (t >= d) ? s[t - d] : 0;
        __syncthreads();
        s[t] += x;
        __syncthreads();
    }
    int run = s[t] - sum;
    for (int i = lo; i < hi; i++) { out[i] = run; run += in[i]; }
}

// per-(WG, coarse-bucket) private streams: single-owner write frontiers
__global__ __launch_bounds__(256) void fillA_kernel(
    const int* __restrict__ src, const int* __restrict__ dst,
    const float* __restrict__ w, int E, int NC,
    const int* __restrict__ wgbase, ull* __restrict__ tmp)
{
    __shared__ int cur[NCMAX];
    int t = threadIdx.x, g = blockIdx.x;
    for (int i = t; i < NC; i += 256) cur[i] = wgbase[i * NWG + g];
    __syncthreads();
    int per = (E + NWG - 1) / NWG;
    int lo = g * per, hi = min(lo + per, E);
    for (int i = lo + t; i < hi; i += 256) {
        int d = dst[i];
        int s = src[i];
        float wv = w[i];
        int b = d >> 9;
        int pos = atomicAdd(&cur[b], 1);
        ull rec = (ull)__float_as_uint(wv)
                | ((ull)(unsigned int)s << 32)
                | ((ull)(unsigned int)(d & (CB - 1)) << 51);
        tmp[pos] = rec;
    }
}

// one WG per coarse bucket (512 nodes, ~8K edges):
// count -> LDS scan(512, stride-1) -> LDS reorder -> sequential csr write
__global__ __launch_bounds__(512) void fillA2B_kernel(
    const ull* __restrict__ tmp, const int* __restrict__ wgbase,
    int NC, int N, int E,
    ull* __restrict__ csr, int* __restrict__ offsets)
{
    __shared__ int cnt[CB];
    __shared__ int ssum[512];
    extern __shared__ ull recs[];    // CAP records
    int b = blockIdx.x, t = threadIdx.x;
    int lo = wgbase[b * NWG];
    int hi = (b == NC - 1) ? E : wgbase[(b + 1) * NWG];
    int M = hi - lo;

    cnt[t] = 0;
    __syncthreads();
    for (int e = lo + t; e < hi; e += 512)
        atomicAdd(&cnt[(int)(tmp[e] >> 51)], 1);
    __syncthreads();

    // exclusive scan over 512 counts (stride-1, conflict-free)
    int v = cnt[t];
    ssum[t] = v;
    __syncthreads();
    for (int d = 1; d < 512; d <<= 1) {
        int x = (t >= d) ? ssum[t - d] : 0;
        __syncthreads();
        ssum[t] += x;
        __syncthreads();
    }
    int excl = ssum[t] - v;

    int node = b * CB + t;
    if (node < N) offsets[node] = lo + excl;
    if (b == NC - 1 && t == 0) offsets[N] = E;
    __syncthreads();
    cnt[t] = excl;       // cursors
    __syncthreads();

    if (M <= CAP) {
        // place into LDS in node-sorted order
        for (int e = lo + t; e < hi; e += 512) {
            ull rec = tmp[e];
            int dl = (int)(rec >> 51);
            int pos = atomicAdd(&cnt[dl], 1);
            recs[pos] = rec & ((1ULL << 51) - 1);
        }
        __syncthreads();
        // stream out: perfectly sequential, full-line writes
        for (int i = t; i < M; i += 512)
            csr[lo + i] = recs[i];
    } else {
        // fallback: direct scatter within the bucket's csr window
        for (int e = lo + t; e < hi; e += 512) {
            ull rec = tmp[e];
            int dl = (int)(rec >> 51);
            int pos = atomicAdd(&cnt[dl], 1);
            csr[lo + pos] = rec & ((1ULL << 51) - 1);
        }
    }
}

// ---------------- z = relu(in @ Wl + bl) -> packed bf16 rows (80 B, stride 80 B) ----------------
template <int RW, int TIN, int TOFF>
__global__ __launch_bounds__(256) void z_kernel(
    const float* __restrict__ in,
    const float* __restrict__ we, const float* __restrict__ be,   // 32x32, 32
    const float* __restrict__ wt, const float* __restrict__ bt,   // TINx8, 8
    unsigned short* __restrict__ zb, int n)
{
    __shared__ float sWe[32 * 32];
    __shared__ float sWt[TIN * 8];
    __shared__ float sBe[32];
    __shared__ float sBt[8];
    for (int i = threadIdx.x; i < 32 * 32; i += 256) sWe[i] = we[i];
    for (int i = threadIdx.x; i < TIN * 8; i += 256) sWt[i] = wt[i];
    if (threadIdx.x < 32) sBe[threadIdx.x] = be[threadIdx.x];
    if (threadIdx.x < 8)  sBt[threadIdx.x] = bt[threadIdx.x];
    __syncthreads();

    int node = blockIdx.x * 256 + threadIdx.x;
    if (node >= n) return;

    float row[RW];
    {
        const float4* rp = (const float4*)(in + (size_t)node * RW);
        #pragma unroll
        for (int q = 0; q < RW / 4; q++) {
            float4 v = rp[q];
            row[4*q] = v.x; row[4*q+1] = v.y; row[4*q+2] = v.z; row[4*q+3] = v.w;
        }
    }

    float o[40];
    #pragma unroll
    for (int j = 0; j < 32; j++) o[j] = sBe[j];
    #pragma unroll
    for (int i = 0; i < 32; i++) {
        float v = row[i];
        #pragma unroll
        for (int j = 0; j < 32; j++) o[j] = fmaf(v, sWe[i * 32 + j], o[j]);
    }
    #pragma unroll
    for (int j = 0; j < 8; j++) o[32 + j] = sBt[j];
    #pragma unroll
    for (int i = 0; i < TIN; i++) {
        float v = row[TOFF + i];
        #pragma unroll
        for (int j = 0; j < 8; j++) o[32 + j] = fmaf(v, sWt[i * 8 + j], o[32 + j]);
    }

    unsigned u[20];
    #pragma unroll
    for (int q = 0; q < 20; q++)
        u[q] = bpack2(relu_(o[2*q]), relu_(o[2*q+1]));
    uint4* zv = (uint4*)(zb + (size_t)node * 40);   // 80 B rows, 16-B aligned
    #pragma unroll
    for (int q = 0; q < 5; q++)
        zv[q] = make_uint4(u[4*q], u[4*q+1], u[4*q+2], u[4*q+3]);
}

// ---------------- fused aggregate + finalize (thread-per-node, bf16 gather) ----------------
template <int RW, int TIN, int TOFF>
__global__ __launch_bounds__(256) void fin_kernel(
    const float* __restrict__ in,            // node features, stride RW (fp32)
    const unsigned short* __restrict__ zb,   // N x 40 bf16 packed (80 B rows)
    const int* __restrict__ offsets,
    const ull* __restrict__ csr,             // [src:19 @32][w:32 @0]
    const float* __restrict__ wre, const float* __restrict__ bre,   // 64x32, 32
    const float* __restrict__ wrt, const float* __restrict__ brt,   // (TIN+8)x8, 8
    float* __restrict__ outbuf, int n)       // n rows, stride 40 fp32
{
    __shared__ float sWe[64 * 32];
    __shared__ float sWt[(TIN + 8) * 8];
    __shared__ float sBe[32];
    __shared__ float sBt[8];
    for (int i = threadIdx.x; i < 64 * 32; i += 256) sWe[i] = wre[i];
    for (int i = threadIdx.x; i < (TIN + 8) * 8; i += 256) sWt[i] = wrt[i];
    if (threadIdx.x < 32) sBe[threadIdx.x] = bre[threadIdx.x];
    if (threadIdx.x < 8)  sBt[threadIdx.x] = brt[threadIdx.x];
    __syncthreads();

    int node = blockIdx.x * 256 + threadIdx.x;
    if (node >= n) return;

    float acc[40];
    #pragma unroll
    for (int j = 0; j < 40; j++) acc[j] = 0.0f;
    float wsum = 1.0f;

    int e0 = offsets[node];
    int e1 = offsets[node + 1];
    for (int e = e0; e < e1; e++) {
        ull pk = csr[e];
        float w = __uint_as_float((unsigned int)pk);
        int sidx = (int)((pk >> 32) & 0x7FFFFull);
        const uint4* zp = (const uint4*)(zb + (size_t)sidx * 40);
        #pragma unroll
        for (int q = 0; q < 5; q++) {
            uint4 v = zp[q];
            acc[8*q+0] = fmaf(w, blo(v.x), acc[8*q+0]);
            acc[8*q+1] = fmaf(w, bhi(v.x), acc[8*q+1]);
            acc[8*q+2] = fmaf(w, blo(v.y), acc[8*q+2]);
            acc[8*q+3] = fmaf(w, bhi(v.y), acc[8*q+3]);
            acc[8*q+4] = fmaf(w, blo(v.z), acc[8*q+4]);
            acc[8*q+5] = fmaf(w, bhi(v.z), acc[8*q+5]);
            acc[8*q+6] = fmaf(w, blo(v.w), acc[8*q+6]);
            acc[8*q+7] = fmaf(w, bhi(v.w), acc[8*q+7]);
        }
        wsum += w;
    }
    float inv = 1.0f / wsum;
    #pragma unroll
    for (int j = 0; j < 40; j++) acc[j] *= inv;

    float row[RW];
    {
        const float4* rp = (const float4*)(in + (size_t)node * RW);
        #pragma unroll
        for (int q = 0; q < RW / 4; q++) {
            float4 v = rp[q];
            row[4*q] = v.x; row[4*q+1] = v.y; row[4*q+2] = v.z; row[4*q+3] = v.w;
        }
    }

    float* op = outbuf + (size_t)node * 40;

    // e-part: [row(0:32), aggE(32)] @ We(64x32) + be
    {
        float o[32];
        #pragma unroll
        for (int j = 0; j < 32; j++) o[j] = sBe[j];
        #pragma unroll
        for (int i = 0; i < 32; i++) {
            float v = row[i];
            #pragma unroll
            for (int j = 0; j < 32; j++) o[j] = fmaf(v, sWe[i * 32 + j], o[j]);
        }
        #pragma unroll
        for (int i = 0; i < 32; i++) {
            float v = acc[i];
            #pragma unroll
            for (int j = 0; j < 32; j++) o[j] = fmaf(v, sWe[(32 + i) * 32 + j], o[j]);
        }
        float4* ov = (float4*)op;
        #pragma unroll
        for (int q = 0; q < 8; q++)
            ov[q] = make_float4(relu_(o[4*q]), relu_(o[4*q+1]), relu_(o[4*q+2]), relu_(o[4*q+3]));
    }

    // t-part: [row(TOFF:TOFF+TIN), aggT(8)] @ Wt((TIN+8)x8) + bt
    {
        float ot[8];
        #pragma unroll
        for (int j = 0; j < 8; j++) ot[j] = sBt[j];
        #pragma unroll
        for (int i = 0; i < TIN; i++) {
            float v = row[TOFF + i];
            #pragma unroll
            for (int j = 0; j < 8; j++) ot[j] = fmaf(v, sWt[i * 8 + j], ot[j]);
        }
        #pragma unroll
        for (int i = 0; i < 8; i++) {
            float v = acc[32 + i];
            #pragma unroll
            for (int j = 0; j < 8; j++) ot[j] = fmaf(v, sWt[(TIN + i) * 8 + j], ot[j]);
        }
        float4* ov = (float4*)op;
        ov[8] = make_float4(relu_(ot[0]), relu_(ot[1]), relu_(ot[2]), relu_(ot[3]));
        ov[9] = make_float4(relu_(ot[4]), relu_(ot[5]), relu_(ot[6]), relu_(ot[7]));
    }
}

// ---------------- loss ----------------

__device__ __forceinline__ void load40(const float* p, float* r) {
    const float4* v = (const float4*)p;
    #pragma unroll
    for (int q = 0; q < 10; q++) {
        float4 t = v[q];
        r[4*q] = t.x; r[4*q+1] = t.y; r[4*q+2] = t.z; r[4*q+3] = t.w;
    }
}

__device__ __forceinline__ float dot40(const float* a, const float* b) {
    float s = 0.0f;
    #pragma unroll
    for (int d = 0; d < 40; d++) s = fmaf(a[d], b[d], s);
    return s;
}

__device__ __forceinline__ void softmax5(const float l[5], float q[5]) {
    float m = l[0];
    #pragma unroll
    for (int c = 1; c < 5; c++) m = fmaxf(m, l[c]);
    float s = 0.0f;
    #pragma unroll
    for (int c = 0; c < 5; c++) { q[c] = expf(l[c] - m); s += q[c]; }
    float inv = 1.0f / s;
    #pragma unroll
    for (int c = 0; c < 5; c++) q[c] *= inv;
}

__device__ __forceinline__ float ent5(const float q[5]) {
    float e = 0.0f;
    #pragma unroll
    for (int c = 0; c < 5; c++) e += q[c] * logf(q[c] + 1e-20f);
    return e;
}

__device__ __forceinline__ float dot5(const float* a, const float* b) {
    float s = 0.0f;
    #pragma unroll
    for (int c = 0; c < 5; c++) s += a[c] * b[c];
    return s;
}

__global__ __launch_bounds__(256) void loss_kernel(
    const float* __restrict__ emb,       // BQ x 5 x 40
    const float* __restrict__ cent,      // 5 x 32
    const float* __restrict__ cent_t,    // 5 x 8
    float* __restrict__ out)
{
    __shared__ float sC[5 * 40];
    for (int i = threadIdx.x; i < 200; i += 256) {
        int c = i / 40, d = i % 40;
        sC[i] = (d < 32) ? cent[c * 32 + d] : cent_t[c * 8 + (d - 32)];
    }
    __syncthreads();

    int i = blockIdx.x * 256 + threadIdx.x;
    float contrib = 0.0f;
    if (i < BQ) {
        const float* base = emb + (size_t)i * 200;

        float ctr[40];
        load40(base, ctr);
        float l[5];
        #pragma unroll
        for (int c = 0; c < 5; c++) l[c] = dot40(ctr, sC + c * 40);
        float qc[5];
        softmax5(l, qc);
        float ent = ent5(qc);

        float rowv[40];
        load40(base + 40, rowv);
        float pd = dot40(ctr, rowv);
        #pragma unroll
        for (int c = 0; c < 5; c++) l[c] = dot40(rowv, sC + c * 40);
        float qp[5];
        softmax5(l, qp);
        float cpd = dot5(qc, qp);
        ent += ent5(qp);

        float nd = -1e30f, cnd = -1e30f;
        #pragma unroll
        for (int k = 0; k < 3; k++) {
            load40(base + (2 + k) * 40, rowv);
            nd = fmaxf(nd, dot40(ctr, rowv));
            #pragma unroll
            for (int c = 0; c < 5; c++) l[c] = dot40(rowv, sC + c * 40);
            float qn[5];
            softmax5(l, qn);
            cnd = fmaxf(cnd, dot5(qc, qn));
            ent += ent5(qn);
        }

        float mm  = fmaxf(nd - pd + 1.0f, 0.0f);
        float cmm = fmaxf(cnd - cpd + 1.0f, 0.0f);
        contrib = (mm + cmm) * (1.0f / (float)BQ) + 0.01f * (1.0f / (float)BS) * ent;
    }

    #pragma unroll
    for (int off = 32; off > 0; off >>= 1) contrib += __shfl_down(contrib, off);
    if ((threadIdx.x & 63) == 0) atomicAdd(out, contrib);
}

// ---------------- launch ----------------

extern "C" void kernel_launch(void* const* d_in, const int* in_sizes, int n_in,
                              void* d_out, int out_size, void* d_ws, size_t ws_size,
                              hipStream_t stream) {
    const float* x      = (const float*)d_in[0];
    const float* weight = (const float*)d_in[1];
    const float* e_w1l  = (const float*)d_in[2];
    const float* e_b1l  = (const float*)d_in[3];
    const float* e_w1r  = (const float*)d_in[4];
    const float* e_b1r  = (const float*)d_in[5];
    const float* e_w2l  = (const float*)d_in[6];
    const float* e_b2l  = (const float*)d_in[7];
    const float* e_w2r  = (const float*)d_in[8];
    const float* e_b2r  = (const float*)d_in[9];
    const float* t_w1l  = (const float*)d_in[10];
    const float* t_b1l  = (const float*)d_in[11];
    const float* t_w1r  = (const float*)d_in[12];
    const float* t_b1r  = (const float*)d_in[13];
    const float* t_w2l  = (const float*)d_in[14];
    const float* t_b2l  = (const float*)d_in[15];
    const float* t_w2r  = (const float*)d_in[16];
    const float* t_b2r  = (const float*)d_in[17];
    const float* cent   = (const float*)d_in[18];
    const float* cent_t = (const float*)d_in[19];
    const int*   eidx   = (const int*)d_in[20];

    const int E = in_sizes[20] / 2;
    const int N = in_sizes[0] / 32;
    const int* srcI = eidx;
    const int* dstI = eidx + E;
    float* out = (float*)d_out;

    const int NC = (N + CB - 1) / CB;    // 977 coarse buckets

    char* p = (char*)d_ws;
    auto alloc = [&](size_t bytes) -> char* {
        char* r = p;
        p += (bytes + 255) & ~(size_t)255;
        return r;
    };
    // region A: tmp (64 MB) aliased with zb (40 MB) — disjoint lifetimes
    char* regionA = alloc((size_t)E * 8);
    ull*  tmp     = (ull*)regionA;
    unsigned short* zb = (unsigned short*)regionA;
    float* hcat   = (float*)alloc((size_t)N * 40 * 4);        // 80 MB
    float* emb    = (float*)alloc((size_t)BS * 40 * 4);       // 16 MB
    ull*   csr    = (ull*)alloc((size_t)E * 8);               // 64 MB
    int*   offsets= (int*)alloc((size_t)(N + 1) * 4);
    int*   hist2D = (int*)alloc((size_t)NC * NWG * 4);
    int*   wgbase = (int*)alloc((size_t)NC * NWG * 4);
    (void)ws_size;

    hipMemsetAsync(d_out, 0, sizeof(float), stream);

    // binning: coarse per-WG hist -> scan -> single-owner binned tmp -> node-sorted CSR
    hist_kernel<<<NWG, 256, 0, stream>>>(dstI, E, NC, hist2D);
    scan_big_kernel<<<1, 1024, 0, stream>>>(hist2D, NC * NWG, wgbase);
    fillA_kernel<<<NWG, 256, 0, stream>>>(srcI, dstI, weight, E, NC, wgbase, tmp);
    fillA2B_kernel<<<NC, 512, (size_t)CAP * 8, stream>>>(tmp, wgbase, NC, N, E, csr, offsets);

    const int nb = (N + 255) / 256;
    // layer 1 (input x, 32-wide; t reads cols 0..31)
    z_kernel<32, 32, 0><<<nb, 256, 0, stream>>>(x, e_w1l, e_b1l, t_w1l, t_b1l, zb, N);
    fin_kernel<32, 32, 0><<<nb, 256, 0, stream>>>(x, zb, offsets, csr,
                                                  e_w1r, e_b1r, t_w1r, t_b1r, hcat, N);
    // layer 2 (input hcat, 40-wide; t reads cols 32..39)
    z_kernel<40, 8, 32><<<nb, 256, 0, stream>>>(hcat, e_w2l, e_b2l, t_w2l, t_b2l, zb, N);
    const int nb2 = (BS + 255) / 256;
    fin_kernel<40, 8, 32><<<nb2, 256, 0, stream>>>(hcat, zb, offsets, csr,
                                                   e_w2r, e_b2r, t_w2r, t_b2r, emb, BS);

    loss_kernel<<<(BQ + 255) / 256, 256, 0, stream>>>(emb, cent, cent_t, out);
}

// Round 8
// 1004.608 us; speedup vs baseline: 1.1479x; 1.1479x over previous
//
#include <hip/hip_runtime.h>

#define BS 100000
#define BQ 20000          // BS / 5
#define NWG 512           // workgroups in hist/fillA partition
#define CB  512           // nodes per bucket
#define NCMAX 1024
#define CAP 12288         // LDS record capacity in fillA2B (mean ~8190, sd ~90)

typedef unsigned long long ull;

__device__ __forceinline__ float relu_(float v) { return fmaxf(v, 0.0f); }

// bf16 helpers (RNE pack, cheap unpack)
__device__ __forceinline__ unsigned bpack2(float a, float b) {
    unsigned ua = __float_as_uint(a), ub = __float_as_uint(b);
    ua = (ua + 0x7FFFu + ((ua >> 16) & 1u)) >> 16;
    ub = (ub + 0x7FFFu + ((ub >> 16) & 1u)) >> 16;
    return ua | (ub << 16);
}
__device__ __forceinline__ float blo(unsigned u) { return __uint_as_float(u << 16); }
__device__ __forceinline__ float bhi(unsigned u) { return __uint_as_float(u & 0xFFFF0000u); }

// ================= binning =================
// tmp record: [dst&511:9 @51][src:19 @32][wbits:32 @0]
// csr record: [src:19 @32][wbits:32 @0]  (node-sorted)
// hist2D layout: [bucket][wg]  (bucket-major)

__global__ __launch_bounds__(256) void hist_kernel(
    const int* __restrict__ dst, int E, int NC, int* __restrict__ hist2D)
{
    __shared__ int lc[NCMAX];
    int t = threadIdx.x, g = blockIdx.x;
    for (int i = t; i < NC; i += 256) lc[i] = 0;
    __syncthreads();
    int per = (E + NWG - 1) / NWG;
    int lo = g * per, hi = min(lo + per, E);
    for (int i = lo + t; i < hi; i += 256) atomicAdd(&lc[dst[i] >> 9], 1);
    __syncthreads();
    for (int b = t; b < NC; b += 256) hist2D[b * NWG + g] = lc[b];
}

// stage A: bucket totals + exclusive scan over buckets -> bucketBase
__global__ __launch_bounds__(1024) void scanA_kernel(
    const int* __restrict__ hist2D, int NC, int* __restrict__ bucketBase)
{
    __shared__ int s[1024];
    int t = threadIdx.x;
    int sum = 0;
    if (t < NC) {
        const int* row = hist2D + (size_t)t * NWG;
        for (int g = 0; g < NWG; g++) sum += row[g];
    }
    s[t] = sum;
    __syncthreads();
    for (int d = 1; d < 1024; d <<= 1) {
        int x = (t >= d) ? s[t - d] : 0;
        __syncthreads();
        s[t] += x;
        __syncthreads();
    }
    if (t < NC) bucketBase[t] = s[t] - sum;
}

// stage B: per-bucket exclusive scan over its NWG counts -> wgbase
__global__ __launch_bounds__(NWG) void scanB_kernel(
    const int* __restrict__ hist2D, const int* __restrict__ bucketBase,
    int* __restrict__ wgbase)
{
    __shared__ int s[NWG];
    int b = blockIdx.x, g = threadIdx.x;
    int v = hist2D[(size_t)b * NWG + g];
    s[g] = v;
    __syncthreads();
    for (int d = 1; d < NWG; d <<= 1) {
        int x = (g >= d) ? s[g - d] : 0;
        __syncthreads();
        s[g] += x;
        __syncthreads();
    }
    wgbase[(size_t)b * NWG + g] = bucketBase[b] + s[g] - v;
}

// per-(WG, bucket) private streams: single-owner write frontiers
__global__ __launch_bounds__(256) void fillA_kernel(
    const int* __restrict__ src, const int* __restrict__ dst,
    const float* __restrict__ w, int E, int NC,
    const int* __restrict__ wgbase, ull* __restrict__ tmp)
{
    __shared__ int cur[NCMAX];
    int t = threadIdx.x, g = blockIdx.x;
    for (int i = t; i < NC; i += 256) cur[i] = wgbase[(size_t)i * NWG + g];
    __syncthreads();
    int per = (E + NWG - 1) / NWG;
    int lo = g * per, hi = min(lo + per, E);
    for (int i = lo + t; i < hi; i += 256) {
        int d = dst[i];
        int s = src[i];
        float wv = w[i];
        int b = d >> 9;
        int pos = atomicAdd(&cur[b], 1);
        ull rec = (ull)__float_as_uint(wv)
                | ((ull)(unsigned int)s << 32)
                | ((ull)(unsigned int)(d & (CB - 1)) << 51);
        tmp[pos] = rec;
    }
}

// one WG per bucket (512 nodes, ~8K edges):
// count -> LDS scan(512) -> LDS reorder -> sequential csr write
__global__ __launch_bounds__(512) void fillA2B_kernel(
    const ull* __restrict__ tmp, const int* __restrict__ wgbase,
    int NC, int N, int E,
    ull* __restrict__ csr, int* __restrict__ offsets)
{
    __shared__ int cnt[CB];
    __shared__ int ssum[512];
    extern __shared__ ull recs[];    // CAP records
    int b = blockIdx.x, t = threadIdx.x;
    int lo = wgbase[(size_t)b * NWG];
    int hi = (b == NC - 1) ? E : wgbase[(size_t)(b + 1) * NWG];
    int M = hi - lo;

    cnt[t] = 0;
    __syncthreads();
    for (int e = lo + t; e < hi; e += 512)
        atomicAdd(&cnt[(int)(tmp[e] >> 51)], 1);
    __syncthreads();

    int v = cnt[t];
    ssum[t] = v;
    __syncthreads();
    for (int d = 1; d < 512; d <<= 1) {
        int x = (t >= d) ? ssum[t - d] : 0;
        __syncthreads();
        ssum[t] += x;
        __syncthreads();
    }
    int excl = ssum[t] - v;

    int node = b * CB + t;
    if (node < N) offsets[node] = lo + excl;
    if (b == NC - 1 && t == 0) offsets[N] = E;
    __syncthreads();
    cnt[t] = excl;
    __syncthreads();

    if (M <= CAP) {
        for (int e = lo + t; e < hi; e += 512) {
            ull rec = tmp[e];
            int dl = (int)(rec >> 51);
            int pos = atomicAdd(&cnt[dl], 1);
            recs[pos] = rec & ((1ULL << 51) - 1);
        }
        __syncthreads();
        for (int i = t; i < M; i += 512)
            csr[lo + i] = recs[i];
    } else {
        for (int e = lo + t; e < hi; e += 512) {
            ull rec = tmp[e];
            int dl = (int)(rec >> 51);
            int pos = atomicAdd(&cnt[dl], 1);
            csr[lo + pos] = rec & ((1ULL << 51) - 1);
        }
    }
}

// ---------------- z = relu(in @ Wl + bl) -> split bf16: zbE (64 B rows), zbT (16 B rows) ----------------
template <int RW, int TIN, int TOFF>
__global__ __launch_bounds__(256) void z_kernel(
    const float* __restrict__ in,
    const float* __restrict__ we, const float* __restrict__ be,   // 32x32, 32
    const float* __restrict__ wt, const float* __restrict__ bt,   // TINx8, 8
    unsigned short* __restrict__ zbE, unsigned short* __restrict__ zbT, int n)
{
    __shared__ float sWe[32 * 32];
    __shared__ float sWt[TIN * 8];
    __shared__ float sBe[32];
    __shared__ float sBt[8];
    for (int i = threadIdx.x; i < 32 * 32; i += 256) sWe[i] = we[i];
    for (int i = threadIdx.x; i < TIN * 8; i += 256) sWt[i] = wt[i];
    if (threadIdx.x < 32) sBe[threadIdx.x] = be[threadIdx.x];
    if (threadIdx.x < 8)  sBt[threadIdx.x] = bt[threadIdx.x];
    __syncthreads();

    int node = blockIdx.x * 256 + threadIdx.x;
    if (node >= n) return;

    float row[RW];
    {
        const float4* rp = (const float4*)(in + (size_t)node * RW);
        #pragma unroll
        for (int q = 0; q < RW / 4; q++) {
            float4 v = rp[q];
            row[4*q] = v.x; row[4*q+1] = v.y; row[4*q+2] = v.z; row[4*q+3] = v.w;
        }
    }

    float o[40];
    #pragma unroll
    for (int j = 0; j < 32; j++) o[j] = sBe[j];
    #pragma unroll
    for (int i = 0; i < 32; i++) {
        float v = row[i];
        #pragma unroll
        for (int j = 0; j < 32; j++) o[j] = fmaf(v, sWe[i * 32 + j], o[j]);
    }
    #pragma unroll
    for (int j = 0; j < 8; j++) o[32 + j] = sBt[j];
    #pragma unroll
    for (int i = 0; i < TIN; i++) {
        float v = row[TOFF + i];
        #pragma unroll
        for (int j = 0; j < 8; j++) o[32 + j] = fmaf(v, sWt[i * 8 + j], o[32 + j]);
    }

    unsigned u[20];
    #pragma unroll
    for (int q = 0; q < 20; q++)
        u[q] = bpack2(relu_(o[2*q]), relu_(o[2*q+1]));
    uint4* ev = (uint4*)(zbE + (size_t)node * 32);   // 64 B, line-aligned
    #pragma unroll
    for (int q = 0; q < 4; q++)
        ev[q] = make_uint4(u[4*q], u[4*q+1], u[4*q+2], u[4*q+3]);
    *(uint4*)(zbT + (size_t)node * 8) = make_uint4(u[16], u[17], u[18], u[19]);
}

// ---------------- fused aggregate + finalize (thread-per-node, bf16 gather) ----------------
template <int RW, int TIN, int TOFF>
__global__ __launch_bounds__(256) void fin_kernel(
    const float* __restrict__ in,             // node features, stride RW (fp32)
    const unsigned short* __restrict__ zbE,   // N x 32 bf16 (64 B rows)
    const unsigned short* __restrict__ zbT,   // N x 8 bf16 (16 B rows)
    const int* __restrict__ offsets,
    const ull* __restrict__ csr,              // [src:19 @32][w:32 @0]
    const float* __restrict__ wre, const float* __restrict__ bre,   // 64x32, 32
    const float* __restrict__ wrt, const float* __restrict__ brt,   // (TIN+8)x8, 8
    float* __restrict__ outbuf, int n)        // n rows, stride 40 fp32
{
    __shared__ float sWe[64 * 32];
    __shared__ float sWt[(TIN + 8) * 8];
    __shared__ float sBe[32];
    __shared__ float sBt[8];
    for (int i = threadIdx.x; i < 64 * 32; i += 256) sWe[i] = wre[i];
    for (int i = threadIdx.x; i < (TIN + 8) * 8; i += 256) sWt[i] = wrt[i];
    if (threadIdx.x < 32) sBe[threadIdx.x] = bre[threadIdx.x];
    if (threadIdx.x < 8)  sBt[threadIdx.x] = brt[threadIdx.x];
    __syncthreads();

    int node = blockIdx.x * 256 + threadIdx.x;
    if (node >= n) return;

    float acc[40];
    #pragma unroll
    for (int j = 0; j < 40; j++) acc[j] = 0.0f;
    float wsum = 1.0f;

    int e0 = offsets[node];
    int e1 = offsets[node + 1];
    for (int e = e0; e < e1; e++) {
        ull pk = csr[e];
        float w = __uint_as_float((unsigned int)pk);
        int sidx = (int)((pk >> 32) & 0x7FFFFull);
        const uint4* ep = (const uint4*)(zbE + (size_t)sidx * 32);
        #pragma unroll
        for (int q = 0; q < 4; q++) {
            uint4 v = ep[q];
            acc[8*q+0] = fmaf(w, blo(v.x), acc[8*q+0]);
            acc[8*q+1] = fmaf(w, bhi(v.x), acc[8*q+1]);
            acc[8*q+2] = fmaf(w, blo(v.y), acc[8*q+2]);
            acc[8*q+3] = fmaf(w, bhi(v.y), acc[8*q+3]);
            acc[8*q+4] = fmaf(w, blo(v.z), acc[8*q+4]);
            acc[8*q+5] = fmaf(w, bhi(v.z), acc[8*q+5]);
            acc[8*q+6] = fmaf(w, blo(v.w), acc[8*q+6]);
            acc[8*q+7] = fmaf(w, bhi(v.w), acc[8*q+7]);
        }
        uint4 tv = *(const uint4*)(zbT + (size_t)sidx * 8);
        acc[32] = fmaf(w, blo(tv.x), acc[32]);
        acc[33] = fmaf(w, bhi(tv.x), acc[33]);
        acc[34] = fmaf(w, blo(tv.y), acc[34]);
        acc[35] = fmaf(w, bhi(tv.y), acc[35]);
        acc[36] = fmaf(w, blo(tv.z), acc[36]);
        acc[37] = fmaf(w, bhi(tv.z), acc[37]);
        acc[38] = fmaf(w, blo(tv.w), acc[38]);
        acc[39] = fmaf(w, bhi(tv.w), acc[39]);
        wsum += w;
    }
    float inv = 1.0f / wsum;
    #pragma unroll
    for (int j = 0; j < 40; j++) acc[j] *= inv;

    float row[RW];
    {
        const float4* rp = (const float4*)(in + (size_t)node * RW);
        #pragma unroll
        for (int q = 0; q < RW / 4; q++) {
            float4 v = rp[q];
            row[4*q] = v.x; row[4*q+1] = v.y; row[4*q+2] = v.z; row[4*q+3] = v.w;
        }
    }

    float* op = outbuf + (size_t)node * 40;

    // e-part: [row(0:32), aggE(32)] @ We(64x32) + be
    {
        float o[32];
        #pragma unroll
        for (int j = 0; j < 32; j++) o[j] = sBe[j];
        #pragma unroll
        for (int i = 0; i < 32; i++) {
            float v = row[i];
            #pragma unroll
            for (int j = 0; j < 32; j++) o[j] = fmaf(v, sWe[i * 32 + j], o[j]);
        }
        #pragma unroll
        for (int i = 0; i < 32; i++) {
            float v = acc[i];
            #pragma unroll
            for (int j = 0; j < 32; j++) o[j] = fmaf(v, sWe[(32 + i) * 32 + j], o[j]);
        }
        float4* ov = (float4*)op;
        #pragma unroll
        for (int q = 0; q < 8; q++)
            ov[q] = make_float4(relu_(o[4*q]), relu_(o[4*q+1]), relu_(o[4*q+2]), relu_(o[4*q+3]));
    }

    // t-part: [row(TOFF:TOFF+TIN), aggT(8)] @ Wt((TIN+8)x8) + bt
    {
        float ot[8];
        #pragma unroll
        for (int j = 0; j < 8; j++) ot[j] = sBt[j];
        #pragma unroll
        for (int i = 0; i < TIN; i++) {
            float v = row[TOFF + i];
            #pragma unroll
            for (int j = 0; j < 8; j++) ot[j] = fmaf(v, sWt[i * 8 + j], ot[j]);
        }
        #pragma unroll
        for (int i = 0; i < 8; i++) {
            float v = acc[32 + i];
            #pragma unroll
            for (int j = 0; j < 8; j++) ot[j] = fmaf(v, sWt[(TIN + i) * 8 + j], ot[j]);
        }
        float4* ov = (float4*)op;
        ov[8] = make_float4(relu_(ot[0]), relu_(ot[1]), relu_(ot[2]), relu_(ot[3]));
        ov[9] = make_float4(relu_(ot[4]), relu_(ot[5]), relu_(ot[6]), relu_(ot[7]));
    }
}

// ---------------- loss ----------------

__device__ __forceinline__ void load40(const float* p, float* r) {
    const float4* v = (const float4*)p;
    #pragma unroll
    for (int q = 0; q < 10; q++) {
        float4 t = v[q];
        r[4*q] = t.x; r[4*q+1] = t.y; r[4*q+2] = t.z; r[4*q+3] = t.w;
    }
}

__device__ __forceinline__ float dot40(const float* a, const float* b) {
    float s = 0.0f;
    #pragma unroll
    for (int d = 0; d < 40; d++) s = fmaf(a[d], b[d], s);
    return s;
}

__device__ __forceinline__ void softmax5(const float l[5], float q[5]) {
    float m = l[0];
    #pragma unroll
    for (int c = 1; c < 5; c++) m = fmaxf(m, l[c]);
    float s = 0.0f;
    #pragma unroll
    for (int c = 0; c < 5; c++) { q[c] = expf(l[c] - m); s += q[c]; }
    float inv = 1.0f / s;
    #pragma unroll
    for (int c = 0; c < 5; c++) q[c] *= inv;
}

__device__ __forceinline__ float ent5(const float q[5]) {
    float e = 0.0f;
    #pragma unroll
    for (int c = 0; c < 5; c++) e += q[c] * logf(q[c] + 1e-20f);
    return e;
}

__device__ __forceinline__ float dot5(const float* a, const float* b) {
    float s = 0.0f;
    #pragma unroll
    for (int c = 0; c < 5; c++) s += a[c] * b[c];
    return s;
}

__global__ __launch_bounds__(256) void loss_kernel(
    const float* __restrict__ emb,       // BQ x 5 x 40
    const float* __restrict__ cent,      // 5 x 32
    const float* __restrict__ cent_t,    // 5 x 8
    float* __restrict__ out)
{
    __shared__ float sC[5 * 40];
    for (int i = threadIdx.x; i < 200; i += 256) {
        int c = i / 40, d = i % 40;
        sC[i] = (d < 32) ? cent[c * 32 + d] : cent_t[c * 8 + (d - 32)];
    }
    __syncthreads();

    int i = blockIdx.x * 256 + threadIdx.x;
    float contrib = 0.0f;
    if (i < BQ) {
        const float* base = emb + (size_t)i * 200;

        float ctr[40];
        load40(base, ctr);
        float l[5];
        #pragma unroll
        for (int c = 0; c < 5; c++) l[c] = dot40(ctr, sC + c * 40);
        float qc[5];
        softmax5(l, qc);
        float ent = ent5(qc);

        float rowv[40];
        load40(base + 40, rowv);
        float pd = dot40(ctr, rowv);
        #pragma unroll
        for (int c = 0; c < 5; c++) l[c] = dot40(rowv, sC + c * 40);
        float qp[5];
        softmax5(l, qp);
        float cpd = dot5(qc, qp);
        ent += ent5(qp);

        float nd = -1e30f, cnd = -1e30f;
        #pragma unroll
        for (int k = 0; k < 3; k++) {
            load40(base + (2 + k) * 40, rowv);
            nd = fmaxf(nd, dot40(ctr, rowv));
            #pragma unroll
            for (int c = 0; c < 5; c++) l[c] = dot40(rowv, sC + c * 40);
            float qn[5];
            softmax5(l, qn);
            cnd = fmaxf(cnd, dot5(qc, qn));
            ent += ent5(qn);
        }

        float mm  = fmaxf(nd - pd + 1.0f, 0.0f);
        float cmm = fmaxf(cnd - cpd + 1.0f, 0.0f);
        contrib = (mm + cmm) * (1.0f / (float)BQ) + 0.01f * (1.0f / (float)BS) * ent;
    }

    #pragma unroll
    for (int off = 32; off > 0; off >>= 1) contrib += __shfl_down(contrib, off);
    if ((threadIdx.x & 63) == 0) atomicAdd(out, contrib);
}

// ---------------- launch ----------------

extern "C" void kernel_launch(void* const* d_in, const int* in_sizes, int n_in,
                              void* d_out, int out_size, void* d_ws, size_t ws_size,
                              hipStream_t stream) {
    const float* x      = (const float*)d_in[0];
    const float* weight = (const float*)d_in[1];
    const float* e_w1l  = (const float*)d_in[2];
    const float* e_b1l  = (const float*)d_in[3];
    const float* e_w1r  = (const float*)d_in[4];
    const float* e_b1r  = (const float*)d_in[5];
    const float* e_w2l  = (const float*)d_in[6];
    const float* e_b2l  = (const float*)d_in[7];
    const float* e_w2r  = (const float*)d_in[8];
    const float* e_b2r  = (const float*)d_in[9];
    const float* t_w1l  = (const float*)d_in[10];
    const float* t_b1l  = (const float*)d_in[11];
    const float* t_w1r  = (const float*)d_in[12];
    const float* t_b1r  = (const float*)d_in[13];
    const float* t_w2l  = (const float*)d_in[14];
    const float* t_b2l  = (const float*)d_in[15];
    const float* t_w2r  = (const float*)d_in[16];
    const float* t_b2r  = (const float*)d_in[17];
    const float* cent   = (const float*)d_in[18];
    const float* cent_t = (const float*)d_in[19];
    const int*   eidx   = (const int*)d_in[20];

    const int E = in_sizes[20] / 2;
    const int N = in_sizes[0] / 32;
    const int* srcI = eidx;
    const int* dstI = eidx + E;
    float* out = (float*)d_out;

    const int NC = (N + CB - 1) / CB;    // 977 buckets

    char* p = (char*)d_ws;
    auto alloc = [&](size_t bytes) -> char* {
        char* r = p;
        p += (bytes + 255) & ~(size_t)255;
        return r;
    };
    // region A: tmp (64 MB) aliased with zbE (32 MB) + zbT (8 MB) — disjoint lifetimes
    char* regionA = alloc((size_t)E * 8);
    ull*  tmp     = (ull*)regionA;
    unsigned short* zbE = (unsigned short*)regionA;
    unsigned short* zbT = (unsigned short*)(regionA + (size_t)N * 32 * 2);
    float* hcat   = (float*)alloc((size_t)N * 40 * 4);        // 80 MB
    float* emb    = (float*)alloc((size_t)BS * 40 * 4);       // 16 MB
    ull*   csr    = (ull*)alloc((size_t)E * 8);               // 64 MB
    int*   offsets= (int*)alloc((size_t)(N + 1) * 4);
    int*   hist2D = (int*)alloc((size_t)NC * NWG * 4);        // 2 MB
    int*   wgbase = (int*)alloc((size_t)NC * NWG * 4);        // 2 MB
    int*   bucketBase = (int*)alloc((size_t)NC * 4);
    (void)ws_size;

    hipMemsetAsync(d_out, 0, sizeof(float), stream);

    // binning: per-WG fine hist -> hierarchical scan -> single-owner streams -> node-sorted CSR
    hist_kernel<<<NWG, 256, 0, stream>>>(dstI, E, NC, hist2D);
    scanA_kernel<<<1, 1024, 0, stream>>>(hist2D, NC, bucketBase);
    scanB_kernel<<<NC, NWG, 0, stream>>>(hist2D, bucketBase, wgbase);
    fillA_kernel<<<NWG, 256, 0, stream>>>(srcI, dstI, weight, E, NC, wgbase, tmp);
    fillA2B_kernel<<<NC, 512, (size_t)CAP * 8, stream>>>(tmp, wgbase, NC, N, E, csr, offsets);

    const int nb = (N + 255) / 256;
    // layer 1 (input x, 32-wide; t reads cols 0..31)
    z_kernel<32, 32, 0><<<nb, 256, 0, stream>>>(x, e_w1l, e_b1l, t_w1l, t_b1l, zbE, zbT, N);
    fin_kernel<32, 32, 0><<<nb, 256, 0, stream>>>(x, zbE, zbT, offsets, csr,
                                                  e_w1r, e_b1r, t_w1r, t_b1r, hcat, N);
    // layer 2 (input hcat, 40-wide; t reads cols 32..39)
    z_kernel<40, 8, 32><<<nb, 256, 0, stream>>>(hcat, e_w2l, e_b2l, t_w2l, t_b2l, zbE, zbT, N);
    const int nb2 = (BS + 255) / 256;
    fin_kernel<40, 8, 32><<<nb2, 256, 0, stream>>>(hcat, zbE, zbT, offsets, csr,
                                                   e_w2r, e_b2r, t_w2r, t_b2r, emb, BS);

    loss_kernel<<<(BQ + 255) / 256, 256, 0, stream>>>(emb, cent, cent_t, out);
}

// Round 9
// 871.700 us; speedup vs baseline: 1.3230x; 1.1525x over previous
//
#include <hip/hip_runtime.h>

#define BS 100000
#define BQ 20000          // BS / 5
#define NWG 512           // workgroups in hist/fillA partition
#define CB  2048          // nodes per coarse bucket
#define NCMAX 256

typedef unsigned long long ull;

__device__ __forceinline__ float relu_(float v) { return fmaxf(v, 0.0f); }

// bf16 helpers (RNE pack, cheap unpack)
__device__ __forceinline__ unsigned bpack2(float a, float b) {
    unsigned ua = __float_as_uint(a), ub = __float_as_uint(b);
    ua = (ua + 0x7FFFu + ((ua >> 16) & 1u)) >> 16;
    ub = (ub + 0x7FFFu + ((ub >> 16) & 1u)) >> 16;
    return ua | (ub << 16);
}
__device__ __forceinline__ float blo(unsigned u) { return __uint_as_float(u << 16); }
__device__ __forceinline__ float bhi(unsigned u) { return __uint_as_float(u & 0xFFFF0000u); }

// ================= binning =================
// tmp record: [dst&2047:11 @51][src:19 @32][wbits:32 @0]
// csr record: [src:19 @32][wbits:32 @0]  (node-sorted)
// hist2D layout: [bucket][wg]  (bucket-major)

__global__ __launch_bounds__(256) void hist_kernel(
    const int* __restrict__ dst, int E, int NC, int* __restrict__ hist2D)
{
    __shared__ int lc[NCMAX];
    int t = threadIdx.x, g = blockIdx.x;
    for (int i = t; i < NC; i += 256) lc[i] = 0;
    __syncthreads();
    int per = (E + NWG - 1) / NWG;
    int lo = g * per, hi = min(lo + per, E);
    for (int i = lo + t; i < hi; i += 256) atomicAdd(&lc[dst[i] >> 11], 1);
    __syncthreads();
    for (int b = t; b < NC; b += 256) hist2D[b * NWG + g] = lc[b];
}

// bucket totals: one block per bucket reduces its NWG row
__global__ __launch_bounds__(256) void reduce_kernel(
    const int* __restrict__ hist2D, int* __restrict__ bucketTot)
{
    __shared__ int s[256];
    int b = blockIdx.x, t = threadIdx.x;
    int sum = 0;
    for (int g = t; g < NWG; g += 256) sum += hist2D[(size_t)b * NWG + g];
    s[t] = sum;
    __syncthreads();
    for (int d = 128; d > 0; d >>= 1) {
        if (t < d) s[t] += s[t + d];
        __syncthreads();
    }
    if (t == 0) bucketTot[b] = s[0];
}

// exclusive scan over NC (<=256) bucket totals
__global__ __launch_bounds__(256) void scanTot_kernel(
    const int* __restrict__ bucketTot, int NC, int* __restrict__ bucketBase)
{
    __shared__ int s[256];
    int t = threadIdx.x;
    int v = (t < NC) ? bucketTot[t] : 0;
    s[t] = v;
    __syncthreads();
    for (int d = 1; d < 256; d <<= 1) {
        int x = (t >= d) ? s[t - d] : 0;
        __syncthreads();
        s[t] += x;
        __syncthreads();
    }
    if (t < NC) bucketBase[t] = s[t] - v;
}

// per-bucket exclusive scan over its NWG counts -> wgbase
__global__ __launch_bounds__(NWG) void scanB_kernel(
    const int* __restrict__ hist2D, const int* __restrict__ bucketBase,
    int* __restrict__ wgbase)
{
    __shared__ int s[NWG];
    int b = blockIdx.x, g = threadIdx.x;
    int v = hist2D[(size_t)b * NWG + g];
    s[g] = v;
    __syncthreads();
    for (int d = 1; d < NWG; d <<= 1) {
        int x = (g >= d) ? s[g - d] : 0;
        __syncthreads();
        s[g] += x;
        __syncthreads();
    }
    wgbase[(size_t)b * NWG + g] = bucketBase[b] + s[g] - v;
}

// per-(WG, bucket) private streams: single-owner write frontiers
// frontier = NC(245) lines/WG x 64 WGs/XCD = 2.0 MB < 4 MB L2 (the round-8 fix)
__global__ __launch_bounds__(256) void fillA_kernel(
    const int* __restrict__ src, const int* __restrict__ dst,
    const float* __restrict__ w, int E, int NC,
    const int* __restrict__ wgbase, ull* __restrict__ tmp)
{
    __shared__ int cur[NCMAX];
    int t = threadIdx.x, g = blockIdx.x;
    for (int i = t; i < NC; i += 256) cur[i] = wgbase[(size_t)i * NWG + g];
    __syncthreads();
    int per = (E + NWG - 1) / NWG;
    int lo = g * per, hi = min(lo + per, E);
    for (int i = lo + t; i < hi; i += 256) {
        int d = dst[i];
        int s = src[i];
        float wv = w[i];
        int b = d >> 11;
        int pos = atomicAdd(&cur[b], 1);
        ull rec = (ull)__float_as_uint(wv)
                | ((ull)(unsigned int)s << 32)
                | ((ull)(unsigned int)(d & (CB - 1)) << 51);
        tmp[pos] = rec;
    }
}

// one WG (512 thr) per coarse bucket (2048 nodes, ~32K edges):
// pass1 count -> LDS scan(2048) -> offsets; pass2 scatter into 256 KB csr window
__global__ __launch_bounds__(512) void fillA2B_kernel(
    const ull* __restrict__ tmp, const int* __restrict__ wgbase,
    int NC, int N, int E,
    ull* __restrict__ csr, int* __restrict__ offsets)
{
    __shared__ int cnt[CB];
    __shared__ int ssum[512];
    int b = blockIdx.x, t = threadIdx.x;
    int lo = wgbase[(size_t)b * NWG];
    int hi = (b == NC - 1) ? E : wgbase[(size_t)(b + 1) * NWG];

    #pragma unroll
    for (int k = 0; k < CB / 512; k++) cnt[t + k * 512] = 0;
    __syncthreads();
    for (int e = lo + t; e < hi; e += 512)
        atomicAdd(&cnt[(int)(tmp[e] >> 51)], 1);
    __syncthreads();

    // scan 2048: thread t owns [4t, 4t+4)
    int base = t * 4;
    int loc[4];
    int run = 0;
    #pragma unroll
    for (int k = 0; k < 4; k++) { loc[k] = run; run += cnt[base + k]; }
    ssum[t] = run;
    __syncthreads();
    for (int d = 1; d < 512; d <<= 1) {
        int x = (t >= d) ? ssum[t - d] : 0;
        __syncthreads();
        ssum[t] += x;
        __syncthreads();
    }
    int excl = ssum[t] - run;

    int nodeBase = b * CB;
    #pragma unroll
    for (int k = 0; k < 4; k++) {
        int node = nodeBase + base + k;
        if (node < N) offsets[node] = lo + excl + loc[k];
        loc[k] += excl;
    }
    if (b == NC - 1 && t == 0) offsets[N] = E;
    __syncthreads();     // all cnt reads done (scan barriers passed)
    #pragma unroll
    for (int k = 0; k < 4; k++) cnt[base + k] = loc[k];
    __syncthreads();

    // pass 2: scatter to node-sorted order within [lo,hi) (256 KB window, single owner)
    for (int e = lo + t; e < hi; e += 512) {
        ull rec = tmp[e];
        int dl = (int)(rec >> 51);
        int pos = atomicAdd(&cnt[dl], 1);
        csr[lo + pos] = rec & ((1ULL << 51) - 1);
    }
}

// ---------------- z = relu(in @ Wl + bl) -> packed bf16 rows (80 B, stride 80 B) ----------------
template <int RW, int TIN, int TOFF>
__global__ __launch_bounds__(256) void z_kernel(
    const float* __restrict__ in,
    const float* __restrict__ we, const float* __restrict__ be,   // 32x32, 32
    const float* __restrict__ wt, const float* __restrict__ bt,   // TINx8, 8
    unsigned short* __restrict__ zb, int n)
{
    __shared__ float sWe[32 * 32];
    __shared__ float sWt[TIN * 8];
    __shared__ float sBe[32];
    __shared__ float sBt[8];
    for (int i = threadIdx.x; i < 32 * 32; i += 256) sWe[i] = we[i];
    for (int i = threadIdx.x; i < TIN * 8; i += 256) sWt[i] = wt[i];
    if (threadIdx.x < 32) sBe[threadIdx.x] = be[threadIdx.x];
    if (threadIdx.x < 8)  sBt[threadIdx.x] = bt[threadIdx.x];
    __syncthreads();

    int node = blockIdx.x * 256 + threadIdx.x;
    if (node >= n) return;

    float row[RW];
    {
        const float4* rp = (const float4*)(in + (size_t)node * RW);
        #pragma unroll
        for (int q = 0; q < RW / 4; q++) {
            float4 v = rp[q];
            row[4*q] = v.x; row[4*q+1] = v.y; row[4*q+2] = v.z; row[4*q+3] = v.w;
        }
    }

    float o[40];
    #pragma unroll
    for (int j = 0; j < 32; j++) o[j] = sBe[j];
    #pragma unroll
    for (int i = 0; i < 32; i++) {
        float v = row[i];
        #pragma unroll
        for (int j = 0; j < 32; j++) o[j] = fmaf(v, sWe[i * 32 + j], o[j]);
    }
    #pragma unroll
    for (int j = 0; j < 8; j++) o[32 + j] = sBt[j];
    #pragma unroll
    for (int i = 0; i < TIN; i++) {
        float v = row[TOFF + i];
        #pragma unroll
        for (int j = 0; j < 8; j++) o[32 + j] = fmaf(v, sWt[i * 8 + j], o[32 + j]);
    }

    unsigned u[20];
    #pragma unroll
    for (int q = 0; q < 20; q++)
        u[q] = bpack2(relu_(o[2*q]), relu_(o[2*q+1]));
    uint4* zv = (uint4*)(zb + (size_t)node * 40);   // 80 B rows, 16-B aligned
    #pragma unroll
    for (int q = 0; q < 5; q++)
        zv[q] = make_uint4(u[4*q], u[4*q+1], u[4*q+2], u[4*q+3]);
}

// ---------------- fused aggregate + finalize (thread-per-node, bf16 gather) ----------------
template <int RW, int TIN, int TOFF>
__global__ __launch_bounds__(256) void fin_kernel(
    const float* __restrict__ in,            // node features, stride RW (fp32)
    const unsigned short* __restrict__ zb,   // N x 40 bf16 packed (80 B rows)
    const int* __restrict__ offsets,
    const ull* __restrict__ csr,             // [src:19 @32][w:32 @0]
    const float* __restrict__ wre, const float* __restrict__ bre,   // 64x32, 32
    const float* __restrict__ wrt, const float* __restrict__ brt,   // (TIN+8)x8, 8
    float* __restrict__ outbuf, int n)       // n rows, stride 40 fp32
{
    __shared__ float sWe[64 * 32];
    __shared__ float sWt[(TIN + 8) * 8];
    __shared__ float sBe[32];
    __shared__ float sBt[8];
    for (int i = threadIdx.x; i < 64 * 32; i += 256) sWe[i] = wre[i];
    for (int i = threadIdx.x; i < (TIN + 8) * 8; i += 256) sWt[i] = wrt[i];
    if (threadIdx.x < 32) sBe[threadIdx.x] = bre[threadIdx.x];
    if (threadIdx.x < 8)  sBt[threadIdx.x] = brt[threadIdx.x];
    __syncthreads();

    int node = blockIdx.x * 256 + threadIdx.x;
    if (node >= n) return;

    float acc[40];
    #pragma unroll
    for (int j = 0; j < 40; j++) acc[j] = 0.0f;
    float wsum = 1.0f;

    int e0 = offsets[node];
    int e1 = offsets[node + 1];
    for (int e = e0; e < e1; e++) {
        ull pk = csr[e];
        float w = __uint_as_float((unsigned int)pk);
        int sidx = (int)((pk >> 32) & 0x7FFFFull);
        const uint4* zp = (const uint4*)(zb + (size_t)sidx * 40);
        #pragma unroll
        for (int q = 0; q < 5; q++) {
            uint4 v = zp[q];
            acc[8*q+0] = fmaf(w, blo(v.x), acc[8*q+0]);
            acc[8*q+1] = fmaf(w, bhi(v.x), acc[8*q+1]);
            acc[8*q+2] = fmaf(w, blo(v.y), acc[8*q+2]);
            acc[8*q+3] = fmaf(w, bhi(v.y), acc[8*q+3]);
            acc[8*q+4] = fmaf(w, blo(v.z), acc[8*q+4]);
            acc[8*q+5] = fmaf(w, bhi(v.z), acc[8*q+5]);
            acc[8*q+6] = fmaf(w, blo(v.w), acc[8*q+6]);
            acc[8*q+7] = fmaf(w, bhi(v.w), acc[8*q+7]);
        }
        wsum += w;
    }
    float inv = 1.0f / wsum;
    #pragma unroll
    for (int j = 0; j < 40; j++) acc[j] *= inv;

    float row[RW];
    {
        const float4* rp = (const float4*)(in + (size_t)node * RW);
        #pragma unroll
        for (int q = 0; q < RW / 4; q++) {
            float4 v = rp[q];
            row[4*q] = v.x; row[4*q+1] = v.y; row[4*q+2] = v.z; row[4*q+3] = v.w;
        }
    }

    float* op = outbuf + (size_t)node * 40;

    // e-part: [row(0:32), aggE(32)] @ We(64x32) + be
    {
        float o[32];
        #pragma unroll
        for (int j = 0; j < 32; j++) o[j] = sBe[j];
        #pragma unroll
        for (int i = 0; i < 32; i++) {
            float v = row[i];
            #pragma unroll
            for (int j = 0; j < 32; j++) o[j] = fmaf(v, sWe[i * 32 + j], o[j]);
        }
        #pragma unroll
        for (int i = 0; i < 32; i++) {
            float v = acc[i];
            #pragma unroll
            for (int j = 0; j < 32; j++) o[j] = fmaf(v, sWe[(32 + i) * 32 + j], o[j]);
        }
        float4* ov = (float4*)op;
        #pragma unroll
        for (int q = 0; q < 8; q++)
            ov[q] = make_float4(relu_(o[4*q]), relu_(o[4*q+1]), relu_(o[4*q+2]), relu_(o[4*q+3]));
    }

    // t-part: [row(TOFF:TOFF+TIN), aggT(8)] @ Wt((TIN+8)x8) + bt
    {
        float ot[8];
        #pragma unroll
        for (int j = 0; j < 8; j++) ot[j] = sBt[j];
        #pragma unroll
        for (int i = 0; i < TIN; i++) {
            float v = row[TOFF + i];
            #pragma unroll
            for (int j = 0; j < 8; j++) ot[j] = fmaf(v, sWt[i * 8 + j], ot[j]);
        }
        #pragma unroll
        for (int i = 0; i < 8; i++) {
            float v = acc[32 + i];
            #pragma unroll
            for (int j = 0; j < 8; j++) ot[j] = fmaf(v, sWt[(TIN + i) * 8 + j], ot[j]);
        }
        float4* ov = (float4*)op;
        ov[8] = make_float4(relu_(ot[0]), relu_(ot[1]), relu_(ot[2]), relu_(ot[3]));
        ov[9] = make_float4(relu_(ot[4]), relu_(ot[5]), relu_(ot[6]), relu_(ot[7]));
    }
}

// ---------------- loss ----------------

__device__ __forceinline__ void load40(const float* p, float* r) {
    const float4* v = (const float4*)p;
    #pragma unroll
    for (int q = 0; q < 10; q++) {
        float4 t = v[q];
        r[4*q] = t.x; r[4*q+1] = t.y; r[4*q+2] = t.z; r[4*q+3] = t.w;
    }
}

__device__ __forceinline__ float dot40(const float* a, const float* b) {
    float s = 0.0f;
    #pragma unroll
    for (int d = 0; d < 40; d++) s = fmaf(a[d], b[d], s);
    return s;
}

__device__ __forceinline__ void softmax5(const float l[5], float q[5]) {
    float m = l[0];
    #pragma unroll
    for (int c = 1; c < 5; c++) m = fmaxf(m, l[c]);
    float s = 0.0f;
    #pragma unroll
    for (int c = 0; c < 5; c++) { q[c] = expf(l[c] - m); s += q[c]; }
    float inv = 1.0f / s;
    #pragma unroll
    for (int c = 0; c < 5; c++) q[c] *= inv;
}

__device__ __forceinline__ float ent5(const float q[5]) {
    float e = 0.0f;
    #pragma unroll
    for (int c = 0; c < 5; c++) e += q[c] * logf(q[c] + 1e-20f);
    return e;
}

__device__ __forceinline__ float dot5(const float* a, const float* b) {
    float s = 0.0f;
    #pragma unroll
    for (int c = 0; c < 5; c++) s += a[c] * b[c];
    return s;
}

__global__ __launch_bounds__(256) void loss_kernel(
    const float* __restrict__ emb,       // BQ x 5 x 40
    const float* __restrict__ cent,      // 5 x 32
    const float* __restrict__ cent_t,    // 5 x 8
    float* __restrict__ out)
{
    __shared__ float sC[5 * 40];
    for (int i = threadIdx.x; i < 200; i += 256) {
        int c = i / 40, d = i % 40;
        sC[i] = (d < 32) ? cent[c * 32 + d] : cent_t[c * 8 + (d - 32)];
    }
    __syncthreads();

    int i = blockIdx.x * 256 + threadIdx.x;
    float contrib = 0.0f;
    if (i < BQ) {
        const float* base = emb + (size_t)i * 200;

        float ctr[40];
        load40(base, ctr);
        float l[5];
        #pragma unroll
        for (int c = 0; c < 5; c++) l[c] = dot40(ctr, sC + c * 40);
        float qc[5];
        softmax5(l, qc);
        float ent = ent5(qc);

        float rowv[40];
        load40(base + 40, rowv);
        float pd = dot40(ctr, rowv);
        #pragma unroll
        for (int c = 0; c < 5; c++) l[c] = dot40(rowv, sC + c * 40);
        float qp[5];
        softmax5(l, qp);
        float cpd = dot5(qc, qp);
        ent += ent5(qp);

        float nd = -1e30f, cnd = -1e30f;
        #pragma unroll
        for (int k = 0; k < 3; k++) {
            load40(base + (2 + k) * 40, rowv);
            nd = fmaxf(nd, dot40(ctr, rowv));
            #pragma unroll
            for (int c = 0; c < 5; c++) l[c] = dot40(rowv, sC + c * 40);
            float qn[5];
            softmax5(l, qn);
            cnd = fmaxf(cnd, dot5(qc, qn));
            ent += ent5(qn);
        }

        float mm  = fmaxf(nd - pd + 1.0f, 0.0f);
        float cmm = fmaxf(cnd - cpd + 1.0f, 0.0f);
        contrib = (mm + cmm) * (1.0f / (float)BQ) + 0.01f * (1.0f / (float)BS) * ent;
    }

    #pragma unroll
    for (int off = 32; off > 0; off >>= 1) contrib += __shfl_down(contrib, off);
    if ((threadIdx.x & 63) == 0) atomicAdd(out, contrib);
}

// ---------------- launch ----------------

extern "C" void kernel_launch(void* const* d_in, const int* in_sizes, int n_in,
                              void* d_out, int out_size, void* d_ws, size_t ws_size,
                              hipStream_t stream) {
    const float* x      = (const float*)d_in[0];
    const float* weight = (const float*)d_in[1];
    const float* e_w1l  = (const float*)d_in[2];
    const float* e_b1l  = (const float*)d_in[3];
    const float* e_w1r  = (const float*)d_in[4];
    const float* e_b1r  = (const float*)d_in[5];
    const float* e_w2l  = (const float*)d_in[6];
    const float* e_b2l  = (const float*)d_in[7];
    const float* e_w2r  = (const float*)d_in[8];
    const float* e_b2r  = (const float*)d_in[9];
    const float* t_w1l  = (const float*)d_in[10];
    const float* t_b1l  = (const float*)d_in[11];
    const float* t_w1r  = (const float*)d_in[12];
    const float* t_b1r  = (const float*)d_in[13];
    const float* t_w2l  = (const float*)d_in[14];
    const float* t_b2l  = (const float*)d_in[15];
    const float* t_w2r  = (const float*)d_in[16];
    const float* t_b2r  = (const float*)d_in[17];
    const float* cent   = (const float*)d_in[18];
    const float* cent_t = (const float*)d_in[19];
    const int*   eidx   = (const int*)d_in[20];

    const int E = in_sizes[20] / 2;
    const int N = in_sizes[0] / 32;
    const int* srcI = eidx;
    const int* dstI = eidx + E;
    float* out = (float*)d_out;

    const int NC = (N + CB - 1) / CB;    // 245 coarse buckets (2048 nodes)

    char* p = (char*)d_ws;
    auto alloc = [&](size_t bytes) -> char* {
        char* r = p;
        p += (bytes + 255) & ~(size_t)255;
        return r;
    };
    // region A: tmp (64 MB) aliased with zb (40 MB) — disjoint lifetimes
    char* regionA = alloc((size_t)E * 8);
    ull*  tmp     = (ull*)regionA;
    unsigned short* zb = (unsigned short*)regionA;
    float* hcat   = (float*)alloc((size_t)N * 40 * 4);        // 80 MB
    float* emb    = (float*)alloc((size_t)BS * 40 * 4);       // 16 MB
    ull*   csr    = (ull*)alloc((size_t)E * 8);               // 64 MB
    int*   offsets= (int*)alloc((size_t)(N + 1) * 4);
    int*   hist2D = (int*)alloc((size_t)NC * NWG * 4);        // 0.5 MB
    int*   wgbase = (int*)alloc((size_t)NC * NWG * 4);        // 0.5 MB
    int*   bucketTot  = (int*)alloc((size_t)NC * 4);
    int*   bucketBase = (int*)alloc((size_t)NC * 4);
    (void)ws_size;

    hipMemsetAsync(d_out, 0, sizeof(float), stream);

    // binning: per-WG coarse hist -> reduce+scan -> single-owner streams -> node-sorted CSR
    hist_kernel<<<NWG, 256, 0, stream>>>(dstI, E, NC, hist2D);
    reduce_kernel<<<NC, 256, 0, stream>>>(hist2D, bucketTot);
    scanTot_kernel<<<1, 256, 0, stream>>>(bucketTot, NC, bucketBase);
    scanB_kernel<<<NC, NWG, 0, stream>>>(hist2D, bucketBase, wgbase);
    fillA_kernel<<<NWG, 256, 0, stream>>>(srcI, dstI, weight, E, NC, wgbase, tmp);
    fillA2B_kernel<<<NC, 512, 0, stream>>>(tmp, wgbase, NC, N, E, csr, offsets);

    const int nb = (N + 255) / 256;
    // layer 1 (input x, 32-wide; t reads cols 0..31)
    z_kernel<32, 32, 0><<<nb, 256, 0, stream>>>(x, e_w1l, e_b1l, t_w1l, t_b1l, zb, N);
    fin_kernel<32, 32, 0><<<nb, 256, 0, stream>>>(x, zb, offsets, csr,
                                                  e_w1r, e_b1r, t_w1r, t_b1r, hcat, N);
    // layer 2 (input hcat, 40-wide; t reads cols 32..39)
    z_kernel<40, 8, 32><<<nb, 256, 0, stream>>>(hcat, e_w2l, e_b2l, t_w2l, t_b2l, zb, N);
    const int nb2 = (BS + 255) / 256;
    fin_kernel<40, 8, 32><<<nb2, 256, 0, stream>>>(hcat, zb, offsets, csr,
                                                   e_w2r, e_b2r, t_w2r, t_b2r, emb, BS);

    loss_kernel<<<(BQ + 255) / 256, 256, 0, stream>>>(emb, cent, cent_t, out);
}

// Round 10
// 802.924 us; speedup vs baseline: 1.4363x; 1.0857x over previous
//
#include <hip/hip_runtime.h>

#define BS 100000
#define BQ 20000          // BS / 5
#define NWG 512           // workgroups in hist/fillA partition
#define CB  2048          // nodes per coarse bucket
#define NCMAX 256

typedef unsigned long long ull;

__device__ __forceinline__ float relu_(float v) { return fmaxf(v, 0.0f); }

// ---- 12-bit unsigned float codec (e5|m7, bias 112; range 2^-15..2^16; RNE) ----
// z >= 0 (post-ReLU) so no sign bit. rel err ~2^-8. 0 encodes as 0 -> decodes 2^-15 (~3e-5, negligible).
__device__ __forceinline__ unsigned enc12(float f) {
    unsigned u = __float_as_uint(f);
    if (u < 0x38000000u) return 0u;                       // below 2^-15 -> 0
    unsigned r = u - 0x38000000u;
    unsigned b = (r + 0x7FFFu + ((r >> 16) & 1u)) >> 16;  // RNE to 12 bits
    return (b > 0xFFFu) ? 0xFFFu : b;
}
__device__ __forceinline__ float dec12(unsigned b) {
    return __uint_as_float((b << 16) + 0x38000000u);
}

// ================= binning =================
// tmp record: [dst&2047:11 @51][src:19 @32][wbits:32 @0]
// csr record: [src:19 @32][wbits:32 @0]  (node-sorted)
// hist2D layout: [bucket][wg]  (bucket-major)

__global__ __launch_bounds__(256) void hist_kernel(
    const int* __restrict__ dst, int E, int NC, int* __restrict__ hist2D)
{
    __shared__ int lc[NCMAX];
    int t = threadIdx.x, g = blockIdx.x;
    for (int i = t; i < NC; i += 256) lc[i] = 0;
    __syncthreads();
    int per = (E + NWG - 1) / NWG;
    int lo = g * per, hi = min(lo + per, E);
    for (int i = lo + t; i < hi; i += 256) atomicAdd(&lc[dst[i] >> 11], 1);
    __syncthreads();
    for (int b = t; b < NC; b += 256) hist2D[b * NWG + g] = lc[b];
}

__global__ __launch_bounds__(256) void reduce_kernel(
    const int* __restrict__ hist2D, int* __restrict__ bucketTot)
{
    __shared__ int s[256];
    int b = blockIdx.x, t = threadIdx.x;
    int sum = 0;
    for (int g = t; g < NWG; g += 256) sum += hist2D[(size_t)b * NWG + g];
    s[t] = sum;
    __syncthreads();
    for (int d = 128; d > 0; d >>= 1) {
        if (t < d) s[t] += s[t + d];
        __syncthreads();
    }
    if (t == 0) bucketTot[b] = s[0];
}

__global__ __launch_bounds__(256) void scanTot_kernel(
    const int* __restrict__ bucketTot, int NC, int* __restrict__ bucketBase)
{
    __shared__ int s[256];
    int t = threadIdx.x;
    int v = (t < NC) ? bucketTot[t] : 0;
    s[t] = v;
    __syncthreads();
    for (int d = 1; d < 256; d <<= 1) {
        int x = (t >= d) ? s[t - d] : 0;
        __syncthreads();
        s[t] += x;
        __syncthreads();
    }
    if (t < NC) bucketBase[t] = s[t] - v;
}

__global__ __launch_bounds__(NWG) void scanB_kernel(
    const int* __restrict__ hist2D, const int* __restrict__ bucketBase,
    int* __restrict__ wgbase)
{
    __shared__ int s[NWG];
    int b = blockIdx.x, g = threadIdx.x;
    int v = hist2D[(size_t)b * NWG + g];
    s[g] = v;
    __syncthreads();
    for (int d = 1; d < NWG; d <<= 1) {
        int x = (g >= d) ? s[g - d] : 0;
        __syncthreads();
        s[g] += x;
        __syncthreads();
    }
    wgbase[(size_t)b * NWG + g] = bucketBase[b] + s[g] - v;
}

// per-(WG, bucket) private streams: frontier 245 lines/WG x 64 WGs/XCD = 2 MB < 4 MB L2
__global__ __launch_bounds__(256) void fillA_kernel(
    const int* __restrict__ src, const int* __restrict__ dst,
    const float* __restrict__ w, int E, int NC,
    const int* __restrict__ wgbase, ull* __restrict__ tmp)
{
    __shared__ int cur[NCMAX];
    int t = threadIdx.x, g = blockIdx.x;
    for (int i = t; i < NC; i += 256) cur[i] = wgbase[(size_t)i * NWG + g];
    __syncthreads();
    int per = (E + NWG - 1) / NWG;
    int lo = g * per, hi = min(lo + per, E);
    for (int i = lo + t; i < hi; i += 256) {
        int d = dst[i];
        int s = src[i];
        float wv = w[i];
        int b = d >> 11;
        int pos = atomicAdd(&cur[b], 1);
        ull rec = (ull)__float_as_uint(wv)
                | ((ull)(unsigned int)s << 32)
                | ((ull)(unsigned int)(d & (CB - 1)) << 51);
        tmp[pos] = rec;
    }
}

// one WG (512 thr) per coarse bucket (2048 nodes, ~32K edges)
__global__ __launch_bounds__(512) void fillA2B_kernel(
    const ull* __restrict__ tmp, const int* __restrict__ wgbase,
    int NC, int N, int E,
    ull* __restrict__ csr, int* __restrict__ offsets)
{
    __shared__ int cnt[CB];
    __shared__ int ssum[512];
    int b = blockIdx.x, t = threadIdx.x;
    int lo = wgbase[(size_t)b * NWG];
    int hi = (b == NC - 1) ? E : wgbase[(size_t)(b + 1) * NWG];

    #pragma unroll
    for (int k = 0; k < CB / 512; k++) cnt[t + k * 512] = 0;
    __syncthreads();
    for (int e = lo + t; e < hi; e += 512)
        atomicAdd(&cnt[(int)(tmp[e] >> 51)], 1);
    __syncthreads();

    int base = t * 4;
    int loc[4];
    int run = 0;
    #pragma unroll
    for (int k = 0; k < 4; k++) { loc[k] = run; run += cnt[base + k]; }
    ssum[t] = run;
    __syncthreads();
    for (int d = 1; d < 512; d <<= 1) {
        int x = (t >= d) ? ssum[t - d] : 0;
        __syncthreads();
        ssum[t] += x;
        __syncthreads();
    }
    int excl = ssum[t] - run;

    int nodeBase = b * CB;
    #pragma unroll
    for (int k = 0; k < 4; k++) {
        int node = nodeBase + base + k;
        if (node < N) offsets[node] = lo + excl + loc[k];
        loc[k] += excl;
    }
    if (b == NC - 1 && t == 0) offsets[N] = E;
    __syncthreads();
    #pragma unroll
    for (int k = 0; k < 4; k++) cnt[base + k] = loc[k];
    __syncthreads();

    for (int e = lo + t; e < hi; e += 512) {
        ull rec = tmp[e];
        int dl = (int)(rec >> 51);
        int pos = atomicAdd(&cnt[dl], 1);
        csr[lo + pos] = rec & ((1ULL << 51) - 1);
    }
}

// ---------------- z = relu(in @ Wl + bl) -> 12-bit packed rows (60 B used, 64 B stride) ----------------
template <int RW, int TIN, int TOFF>
__global__ __launch_bounds__(256) void z_kernel(
    const float* __restrict__ in,
    const float* __restrict__ we, const float* __restrict__ be,   // 32x32, 32
    const float* __restrict__ wt, const float* __restrict__ bt,   // TINx8, 8
    unsigned* __restrict__ zq, int n)                             // n x 16 uints
{
    __shared__ float sWe[32 * 32];
    __shared__ float sWt[TIN * 8];
    __shared__ float sBe[32];
    __shared__ float sBt[8];
    for (int i = threadIdx.x; i < 32 * 32; i += 256) sWe[i] = we[i];
    for (int i = threadIdx.x; i < TIN * 8; i += 256) sWt[i] = wt[i];
    if (threadIdx.x < 32) sBe[threadIdx.x] = be[threadIdx.x];
    if (threadIdx.x < 8)  sBt[threadIdx.x] = bt[threadIdx.x];
    __syncthreads();

    int node = blockIdx.x * 256 + threadIdx.x;
    if (node >= n) return;

    float row[RW];
    {
        const float4* rp = (const float4*)(in + (size_t)node * RW);
        #pragma unroll
        for (int q = 0; q < RW / 4; q++) {
            float4 v = rp[q];
            row[4*q] = v.x; row[4*q+1] = v.y; row[4*q+2] = v.z; row[4*q+3] = v.w;
        }
    }

    float o[40];
    #pragma unroll
    for (int j = 0; j < 32; j++) o[j] = sBe[j];
    #pragma unroll
    for (int i = 0; i < 32; i++) {
        float v = row[i];
        #pragma unroll
        for (int j = 0; j < 32; j++) o[j] = fmaf(v, sWe[i * 32 + j], o[j]);
    }
    #pragma unroll
    for (int j = 0; j < 8; j++) o[32 + j] = sBt[j];
    #pragma unroll
    for (int i = 0; i < TIN; i++) {
        float v = row[TOFF + i];
        #pragma unroll
        for (int j = 0; j < 8; j++) o[32 + j] = fmaf(v, sWt[i * 8 + j], o[32 + j]);
    }

    unsigned b[40];
    #pragma unroll
    for (int i = 0; i < 40; i++) b[i] = enc12(relu_(o[i]));

    unsigned wd[16];
    #pragma unroll
    for (int k = 0; k < 5; k++) {
        unsigned v0 = b[8*k+0], v1 = b[8*k+1], v2 = b[8*k+2], v3 = b[8*k+3];
        unsigned v4 = b[8*k+4], v5 = b[8*k+5], v6 = b[8*k+6], v7 = b[8*k+7];
        wd[3*k+0] = v0 | (v1 << 12) | (v2 << 24);
        wd[3*k+1] = (v2 >> 8) | (v3 << 4) | (v4 << 16) | (v5 << 28);
        wd[3*k+2] = (v5 >> 4) | (v6 << 8) | (v7 << 20);
    }
    wd[15] = 0;

    uint4* zv = (uint4*)(zq + (size_t)node * 16);   // 64 B, line-aligned
    #pragma unroll
    for (int q = 0; q < 4; q++)
        zv[q] = make_uint4(wd[4*q], wd[4*q+1], wd[4*q+2], wd[4*q+3]);
}

// ---------------- fused aggregate + finalize (thread-per-node, 12-bit gather: 1 line/edge) ----------------
template <int RW, int TIN, int TOFF>
__global__ __launch_bounds__(256) void fin_kernel(
    const float* __restrict__ in,            // node features, stride RW (fp32)
    const unsigned* __restrict__ zq,         // N x 16 uints (12-bit packed z)
    const int* __restrict__ offsets,
    const ull* __restrict__ csr,             // [src:19 @32][w:32 @0]
    const float* __restrict__ wre, const float* __restrict__ bre,   // 64x32, 32
    const float* __restrict__ wrt, const float* __restrict__ brt,   // (TIN+8)x8, 8
    float* __restrict__ outbuf, int n)       // n rows, stride 40 fp32
{
    __shared__ float sWe[64 * 32];
    __shared__ float sWt[(TIN + 8) * 8];
    __shared__ float sBe[32];
    __shared__ float sBt[8];
    for (int i = threadIdx.x; i < 64 * 32; i += 256) sWe[i] = wre[i];
    for (int i = threadIdx.x; i < (TIN + 8) * 8; i += 256) sWt[i] = wrt[i];
    if (threadIdx.x < 32) sBe[threadIdx.x] = bre[threadIdx.x];
    if (threadIdx.x < 8)  sBt[threadIdx.x] = brt[threadIdx.x];
    __syncthreads();

    int node = blockIdx.x * 256 + threadIdx.x;
    if (node >= n) return;

    float acc[40];
    #pragma unroll
    for (int j = 0; j < 40; j++) acc[j] = 0.0f;
    float wsum = 1.0f;

    int e0 = offsets[node];
    int e1 = offsets[node + 1];
    for (int e = e0; e < e1; e++) {
        ull pk = csr[e];
        float w = __uint_as_float((unsigned int)pk);
        int sidx = (int)((pk >> 32) & 0x7FFFFull);
        const uint4* zp = (const uint4*)(zq + (size_t)sidx * 16);
        uint4 A = zp[0], B = zp[1], C = zp[2], D = zp[3];
        unsigned wds[15] = {A.x, A.y, A.z, A.w, B.x, B.y, B.z, B.w,
                            C.x, C.y, C.z, C.w, D.x, D.y, D.z};
        #pragma unroll
        for (int k = 0; k < 5; k++) {
            unsigned xw = wds[3*k+0], yw = wds[3*k+1], zw = wds[3*k+2];
            acc[8*k+0] = fmaf(w, dec12(xw & 0xFFFu),                    acc[8*k+0]);
            acc[8*k+1] = fmaf(w, dec12((xw >> 12) & 0xFFFu),            acc[8*k+1]);
            acc[8*k+2] = fmaf(w, dec12(((xw >> 24) | (yw << 8)) & 0xFFFu), acc[8*k+2]);
            acc[8*k+3] = fmaf(w, dec12((yw >> 4) & 0xFFFu),             acc[8*k+3]);
            acc[8*k+4] = fmaf(w, dec12((yw >> 16) & 0xFFFu),            acc[8*k+4]);
            acc[8*k+5] = fmaf(w, dec12(((yw >> 28) | (zw << 4)) & 0xFFFu), acc[8*k+5]);
            acc[8*k+6] = fmaf(w, dec12((zw >> 8) & 0xFFFu),             acc[8*k+6]);
            acc[8*k+7] = fmaf(w, dec12((zw >> 20) & 0xFFFu),            acc[8*k+7]);
        }
        wsum += w;
    }
    float inv = 1.0f / wsum;
    #pragma unroll
    for (int j = 0; j < 40; j++) acc[j] *= inv;

    float row[RW];
    {
        const float4* rp = (const float4*)(in + (size_t)node * RW);
        #pragma unroll
        for (int q = 0; q < RW / 4; q++) {
            float4 v = rp[q];
            row[4*q] = v.x; row[4*q+1] = v.y; row[4*q+2] = v.z; row[4*q+3] = v.w;
        }
    }

    float* op = outbuf + (size_t)node * 40;

    // e-part: [row(0:32), aggE(32)] @ We(64x32) + be
    {
        float o[32];
        #pragma unroll
        for (int j = 0; j < 32; j++) o[j] = sBe[j];
        #pragma unroll
        for (int i = 0; i < 32; i++) {
            float v = row[i];
            #pragma unroll
            for (int j = 0; j < 32; j++) o[j] = fmaf(v, sWe[i * 32 + j], o[j]);
        }
        #pragma unroll
        for (int i = 0; i < 32; i++) {
            float v = acc[i];
            #pragma unroll
            for (int j = 0; j < 32; j++) o[j] = fmaf(v, sWe[(32 + i) * 32 + j], o[j]);
        }
        float4* ov = (float4*)op;
        #pragma unroll
        for (int q = 0; q < 8; q++)
            ov[q] = make_float4(relu_(o[4*q]), relu_(o[4*q+1]), relu_(o[4*q+2]), relu_(o[4*q+3]));
    }

    // t-part: [row(TOFF:TOFF+TIN), aggT(8)] @ Wt((TIN+8)x8) + bt
    {
        float ot[8];
        #pragma unroll
        for (int j = 0; j < 8; j++) ot[j] = sBt[j];
        #pragma unroll
        for (int i = 0; i < TIN; i++) {
            float v = row[TOFF + i];
            #pragma unroll
            for (int j = 0; j < 8; j++) ot[j] = fmaf(v, sWt[i * 8 + j], ot[j]);
        }
        #pragma unroll
        for (int i = 0; i < 8; i++) {
            float v = acc[32 + i];
            #pragma unroll
            for (int j = 0; j < 8; j++) ot[j] = fmaf(v, sWt[(TIN + i) * 8 + j], ot[j]);
        }
        float4* ov = (float4*)op;
        ov[8] = make_float4(relu_(ot[0]), relu_(ot[1]), relu_(ot[2]), relu_(ot[3]));
        ov[9] = make_float4(relu_(ot[4]), relu_(ot[5]), relu_(ot[6]), relu_(ot[7]));
    }
}

// ---------------- loss ----------------

__device__ __forceinline__ void load40(const float* p, float* r) {
    const float4* v = (const float4*)p;
    #pragma unroll
    for (int q = 0; q < 10; q++) {
        float4 t = v[q];
        r[4*q] = t.x; r[4*q+1] = t.y; r[4*q+2] = t.z; r[4*q+3] = t.w;
    }
}

__device__ __forceinline__ float dot40(const float* a, const float* b) {
    float s = 0.0f;
    #pragma unroll
    for (int d = 0; d < 40; d++) s = fmaf(a[d], b[d], s);
    return s;
}

__device__ __forceinline__ void softmax5(const float l[5], float q[5]) {
    float m = l[0];
    #pragma unroll
    for (int c = 1; c < 5; c++) m = fmaxf(m, l[c]);
    float s = 0.0f;
    #pragma unroll
    for (int c = 0; c < 5; c++) { q[c] = expf(l[c] - m); s += q[c]; }
    float inv = 1.0f / s;
    #pragma unroll
    for (int c = 0; c < 5; c++) q[c] *= inv;
}

__device__ __forceinline__ float ent5(const float q[5]) {
    float e = 0.0f;
    #pragma unroll
    for (int c = 0; c < 5; c++) e += q[c] * logf(q[c] + 1e-20f);
    return e;
}

__device__ __forceinline__ float dot5(const float* a, const float* b) {
    float s = 0.0f;
    #pragma unroll
    for (int c = 0; c < 5; c++) s += a[c] * b[c];
    return s;
}

__global__ __launch_bounds__(256) void loss_kernel(
    const float* __restrict__ emb,       // BQ x 5 x 40
    const float* __restrict__ cent,      // 5 x 32
    const float* __restrict__ cent_t,    // 5 x 8
    float* __restrict__ out)
{
    __shared__ float sC[5 * 40];
    for (int i = threadIdx.x; i < 200; i += 256) {
        int c = i / 40, d = i % 40;
        sC[i] = (d < 32) ? cent[c * 32 + d] : cent_t[c * 8 + (d - 32)];
    }
    __syncthreads();

    int i = blockIdx.x * 256 + threadIdx.x;
    float contrib = 0.0f;
    if (i < BQ) {
        const float* base = emb + (size_t)i * 200;

        float ctr[40];
        load40(base, ctr);
        float l[5];
        #pragma unroll
        for (int c = 0; c < 5; c++) l[c] = dot40(ctr, sC + c * 40);
        float qc[5];
        softmax5(l, qc);
        float ent = ent5(qc);

        float rowv[40];
        load40(base + 40, rowv);
        float pd = dot40(ctr, rowv);
        #pragma unroll
        for (int c = 0; c < 5; c++) l[c] = dot40(rowv, sC + c * 40);
        float qp[5];
        softmax5(l, qp);
        float cpd = dot5(qc, qp);
        ent += ent5(qp);

        float nd = -1e30f, cnd = -1e30f;
        #pragma unroll
        for (int k = 0; k < 3; k++) {
            load40(base + (2 + k) * 40, rowv);
            nd = fmaxf(nd, dot40(ctr, rowv));
            #pragma unroll
            for (int c = 0; c < 5; c++) l[c] = dot40(rowv, sC + c * 40);
            float qn[5];
            softmax5(l, qn);
            cnd = fmaxf(cnd, dot5(qc, qn));
            ent += ent5(qn);
        }

        float mm  = fmaxf(nd - pd + 1.0f, 0.0f);
        float cmm = fmaxf(cnd - cpd + 1.0f, 0.0f);
        contrib = (mm + cmm) * (1.0f / (float)BQ) + 0.01f * (1.0f / (float)BS) * ent;
    }

    #pragma unroll
    for (int off = 32; off > 0; off >>= 1) contrib += __shfl_down(contrib, off);
    if ((threadIdx.x & 63) == 0) atomicAdd(out, contrib);
}

// ---------------- launch ----------------

extern "C" void kernel_launch(void* const* d_in, const int* in_sizes, int n_in,
                              void* d_out, int out_size, void* d_ws, size_t ws_size,
                              hipStream_t stream) {
    const float* x      = (const float*)d_in[0];
    const float* weight = (const float*)d_in[1];
    const float* e_w1l  = (const float*)d_in[2];
    const float* e_b1l  = (const float*)d_in[3];
    const float* e_w1r  = (const float*)d_in[4];
    const float* e_b1r  = (const float*)d_in[5];
    const float* e_w2l  = (const float*)d_in[6];
    const float* e_b2l  = (const float*)d_in[7];
    const float* e_w2r  = (const float*)d_in[8];
    const float* e_b2r  = (const float*)d_in[9];
    const float* t_w1l  = (const float*)d_in[10];
    const float* t_b1l  = (const float*)d_in[11];
    const float* t_w1r  = (const float*)d_in[12];
    const float* t_b1r  = (const float*)d_in[13];
    const float* t_w2l  = (const float*)d_in[14];
    const float* t_b2l  = (const float*)d_in[15];
    const float* t_w2r  = (const float*)d_in[16];
    const float* t_b2r  = (const float*)d_in[17];
    const float* cent   = (const float*)d_in[18];
    const float* cent_t = (const float*)d_in[19];
    const int*   eidx   = (const int*)d_in[20];

    const int E = in_sizes[20] / 2;
    const int N = in_sizes[0] / 32;
    const int* srcI = eidx;
    const int* dstI = eidx + E;
    float* out = (float*)d_out;

    const int NC = (N + CB - 1) / CB;    // 245 coarse buckets (2048 nodes)

    char* p = (char*)d_ws;
    auto alloc = [&](size_t bytes) -> char* {
        char* r = p;
        p += (bytes + 255) & ~(size_t)255;
        return r;
    };
    // region A: tmp (64 MB) aliased with zq (32 MB) — disjoint lifetimes
    char* regionA = alloc((size_t)E * 8);
    ull*  tmp     = (ull*)regionA;
    unsigned* zq  = (unsigned*)regionA;
    float* hcat   = (float*)alloc((size_t)N * 40 * 4);        // 80 MB
    float* emb    = (float*)alloc((size_t)BS * 40 * 4);       // 16 MB
    ull*   csr    = (ull*)alloc((size_t)E * 8);               // 64 MB
    int*   offsets= (int*)alloc((size_t)(N + 1) * 4);
    int*   hist2D = (int*)alloc((size_t)NC * NWG * 4);        // 0.5 MB
    int*   wgbase = (int*)alloc((size_t)NC * NWG * 4);        // 0.5 MB
    int*   bucketTot  = (int*)alloc((size_t)NC * 4);
    int*   bucketBase = (int*)alloc((size_t)NC * 4);
    (void)ws_size;

    hipMemsetAsync(d_out, 0, sizeof(float), stream);

    // binning
    hist_kernel<<<NWG, 256, 0, stream>>>(dstI, E, NC, hist2D);
    reduce_kernel<<<NC, 256, 0, stream>>>(hist2D, bucketTot);
    scanTot_kernel<<<1, 256, 0, stream>>>(bucketTot, NC, bucketBase);
    scanB_kernel<<<NC, NWG, 0, stream>>>(hist2D, bucketBase, wgbase);
    fillA_kernel<<<NWG, 256, 0, stream>>>(srcI, dstI, weight, E, NC, wgbase, tmp);
    fillA2B_kernel<<<NC, 512, 0, stream>>>(tmp, wgbase, NC, N, E, csr, offsets);

    const int nb = (N + 255) / 256;
    // layer 1 (input x, 32-wide; t reads cols 0..31)
    z_kernel<32, 32, 0><<<nb, 256, 0, stream>>>(x, e_w1l, e_b1l, t_w1l, t_b1l, zq, N);
    fin_kernel<32, 32, 0><<<nb, 256, 0, stream>>>(x, zq, offsets, csr,
                                                  e_w1r, e_b1r, t_w1r, t_b1r, hcat, N);
    // layer 2 (input hcat, 40-wide; t reads cols 32..39)
    z_kernel<40, 8, 32><<<nb, 256, 0, stream>>>(hcat, e_w2l, e_b2l, t_w2l, t_b2l, zq, N);
    const int nb2 = (BS + 255) / 256;
    fin_kernel<40, 8, 32><<<nb2, 256, 0, stream>>>(hcat, zq, offsets, csr,
                                                   e_w2r, e_b2r, t_w2r, t_b2r, emb, BS);

    loss_kernel<<<(BQ + 255) / 256, 256, 0, stream>>>(emb, cent, cent_t, out);
}

// Round 11
// 652.270 us; speedup vs baseline: 1.7680x; 1.2310x over previous
//
#include <hip/hip_runtime.h>

#define BS 100000
#define BQ 20000          // BS / 5
#define NWG 512           // workgroups in hist/fillA partition
#define CB  2048          // nodes per coarse bucket
#define NCMAX 256

typedef unsigned long long ull;

__device__ __forceinline__ float relu_(float v) { return fmaxf(v, 0.0f); }

// ---- 12-bit unsigned float codec (e5|m7, bias 112; range 2^-15..2^16; RNE) ----
__device__ __forceinline__ unsigned enc12(float f) {
    unsigned u = __float_as_uint(f);
    if (u < 0x38000000u) return 0u;
    unsigned r = u - 0x38000000u;
    unsigned b = (r + 0x7FFFu + ((r >> 16) & 1u)) >> 16;
    return (b > 0xFFFu) ? 0xFFFu : b;
}
__device__ __forceinline__ float dec12(unsigned b) {
    return __uint_as_float((b << 16) + 0x38000000u);
}

// ================= binning (unchanged from round 9/10) =================

__global__ __launch_bounds__(256) void hist_kernel(
    const int* __restrict__ dst, int E, int NC, int* __restrict__ hist2D)
{
    __shared__ int lc[NCMAX];
    int t = threadIdx.x, g = blockIdx.x;
    for (int i = t; i < NC; i += 256) lc[i] = 0;
    __syncthreads();
    int per = (E + NWG - 1) / NWG;
    int lo = g * per, hi = min(lo + per, E);
    for (int i = lo + t; i < hi; i += 256) atomicAdd(&lc[dst[i] >> 11], 1);
    __syncthreads();
    for (int b = t; b < NC; b += 256) hist2D[b * NWG + g] = lc[b];
}

__global__ __launch_bounds__(256) void reduce_kernel(
    const int* __restrict__ hist2D, int* __restrict__ bucketTot)
{
    __shared__ int s[256];
    int b = blockIdx.x, t = threadIdx.x;
    int sum = 0;
    for (int g = t; g < NWG; g += 256) sum += hist2D[(size_t)b * NWG + g];
    s[t] = sum;
    __syncthreads();
    for (int d = 128; d > 0; d >>= 1) {
        if (t < d) s[t] += s[t + d];
        __syncthreads();
    }
    if (t == 0) bucketTot[b] = s[0];
}

__global__ __launch_bounds__(256) void scanTot_kernel(
    const int* __restrict__ bucketTot, int NC, int* __restrict__ bucketBase)
{
    __shared__ int s[256];
    int t = threadIdx.x;
    int v = (t < NC) ? bucketTot[t] : 0;
    s[t] = v;
    __syncthreads();
    for (int d = 1; d < 256; d <<= 1) {
        int x = (t >= d) ? s[t - d] : 0;
        __syncthreads();
        s[t] += x;
        __syncthreads();
    }
    if (t < NC) bucketBase[t] = s[t] - v;
}

__global__ __launch_bounds__(NWG) void scanB_kernel(
    const int* __restrict__ hist2D, const int* __restrict__ bucketBase,
    int* __restrict__ wgbase)
{
    __shared__ int s[NWG];
    int b = blockIdx.x, g = threadIdx.x;
    int v = hist2D[(size_t)b * NWG + g];
    s[g] = v;
    __syncthreads();
    for (int d = 1; d < NWG; d <<= 1) {
        int x = (g >= d) ? s[g - d] : 0;
        __syncthreads();
        s[g] += x;
        __syncthreads();
    }
    wgbase[(size_t)b * NWG + g] = bucketBase[b] + s[g] - v;
}

__global__ __launch_bounds__(256) void fillA_kernel(
    const int* __restrict__ src, const int* __restrict__ dst,
    const float* __restrict__ w, int E, int NC,
    const int* __restrict__ wgbase, ull* __restrict__ tmp)
{
    __shared__ int cur[NCMAX];
    int t = threadIdx.x, g = blockIdx.x;
    for (int i = t; i < NC; i += 256) cur[i] = wgbase[(size_t)i * NWG + g];
    __syncthreads();
    int per = (E + NWG - 1) / NWG;
    int lo = g * per, hi = min(lo + per, E);
    for (int i = lo + t; i < hi; i += 256) {
        int d = dst[i];
        int s = src[i];
        float wv = w[i];
        int b = d >> 11;
        int pos = atomicAdd(&cur[b], 1);
        ull rec = (ull)__float_as_uint(wv)
                | ((ull)(unsigned int)s << 32)
                | ((ull)(unsigned int)(d & (CB - 1)) << 51);
        tmp[pos] = rec;
    }
}

__global__ __launch_bounds__(512) void fillA2B_kernel(
    const ull* __restrict__ tmp, const int* __restrict__ wgbase,
    int NC, int N, int E,
    ull* __restrict__ csr, int* __restrict__ offsets)
{
    __shared__ int cnt[CB];
    __shared__ int ssum[512];
    int b = blockIdx.x, t = threadIdx.x;
    int lo = wgbase[(size_t)b * NWG];
    int hi = (b == NC - 1) ? E : wgbase[(size_t)(b + 1) * NWG];

    #pragma unroll
    for (int k = 0; k < CB / 512; k++) cnt[t + k * 512] = 0;
    __syncthreads();
    for (int e = lo + t; e < hi; e += 512)
        atomicAdd(&cnt[(int)(tmp[e] >> 51)], 1);
    __syncthreads();

    int base = t * 4;
    int loc[4];
    int run = 0;
    #pragma unroll
    for (int k = 0; k < 4; k++) { loc[k] = run; run += cnt[base + k]; }
    ssum[t] = run;
    __syncthreads();
    for (int d = 1; d < 512; d <<= 1) {
        int x = (t >= d) ? ssum[t - d] : 0;
        __syncthreads();
        ssum[t] += x;
        __syncthreads();
    }
    int excl = ssum[t] - run;

    int nodeBase = b * CB;
    #pragma unroll
    for (int k = 0; k < 4; k++) {
        int node = nodeBase + base + k;
        if (node < N) offsets[node] = lo + excl + loc[k];
        loc[k] += excl;
    }
    if (b == NC - 1 && t == 0) offsets[N] = E;
    __syncthreads();
    #pragma unroll
    for (int k = 0; k < 4; k++) cnt[base + k] = loc[k];
    __syncthreads();

    for (int e = lo + t; e < hi; e += 512) {
        ull rec = tmp[e];
        int dl = (int)(rec >> 51);
        int pos = atomicAdd(&cnt[dl], 1);
        csr[lo + pos] = rec & ((1ULL << 51) - 1);
    }
}

// ---------------- z1 = relu(x @ Wl + bl) -> 12-bit packed rows (64 B stride) ----------------
__global__ __launch_bounds__(256) void z1_kernel(
    const float* __restrict__ in,
    const float* __restrict__ we, const float* __restrict__ be,
    const float* __restrict__ wt, const float* __restrict__ bt,
    unsigned* __restrict__ zq, int n)
{
    __shared__ float sWe[32 * 32];
    __shared__ float sWt[32 * 8];
    __shared__ float sBe[32];
    __shared__ float sBt[8];
    for (int i = threadIdx.x; i < 32 * 32; i += 256) sWe[i] = we[i];
    for (int i = threadIdx.x; i < 32 * 8; i += 256) sWt[i] = wt[i];
    if (threadIdx.x < 32) sBe[threadIdx.x] = be[threadIdx.x];
    if (threadIdx.x < 8)  sBt[threadIdx.x] = bt[threadIdx.x];
    __syncthreads();

    int node = blockIdx.x * 256 + threadIdx.x;
    if (node >= n) return;

    float row[32];
    {
        const float4* rp = (const float4*)(in + (size_t)node * 32);
        #pragma unroll
        for (int q = 0; q < 8; q++) {
            float4 v = rp[q];
            row[4*q] = v.x; row[4*q+1] = v.y; row[4*q+2] = v.z; row[4*q+3] = v.w;
        }
    }

    float o[40];
    #pragma unroll
    for (int j = 0; j < 32; j++) o[j] = sBe[j];
    #pragma unroll
    for (int i = 0; i < 32; i++) {
        float v = row[i];
        #pragma unroll
        for (int j = 0; j < 32; j++) o[j] = fmaf(v, sWe[i * 32 + j], o[j]);
    }
    #pragma unroll
    for (int j = 0; j < 8; j++) o[32 + j] = sBt[j];
    #pragma unroll
    for (int i = 0; i < 32; i++) {
        float v = row[i];
        #pragma unroll
        for (int j = 0; j < 8; j++) o[32 + j] = fmaf(v, sWt[i * 8 + j], o[32 + j]);
    }

    unsigned b[40];
    #pragma unroll
    for (int i = 0; i < 40; i++) b[i] = enc12(relu_(o[i]));
    unsigned wd[16];
    #pragma unroll
    for (int k = 0; k < 5; k++) {
        wd[3*k+0] = b[8*k+0] | (b[8*k+1] << 12) | (b[8*k+2] << 24);
        wd[3*k+1] = (b[8*k+2] >> 8) | (b[8*k+3] << 4) | (b[8*k+4] << 16) | (b[8*k+5] << 28);
        wd[3*k+2] = (b[8*k+5] >> 4) | (b[8*k+6] << 8) | (b[8*k+7] << 20);
    }
    wd[15] = 0;
    uint4* zv = (uint4*)(zq + (size_t)node * 16);
    #pragma unroll
    for (int q = 0; q < 4; q++)
        zv[q] = make_uint4(wd[4*q], wd[4*q+1], wd[4*q+2], wd[4*q+3]);
}

// ---------------- decode+accumulate one edge ----------------
__device__ __forceinline__ void acc_edge(float* acc, float w,
    const uint4& A, const uint4& B, const uint4& C, const uint4& D)
{
    unsigned wds[15] = {A.x, A.y, A.z, A.w, B.x, B.y, B.z, B.w,
                        C.x, C.y, C.z, C.w, D.x, D.y, D.z};
    #pragma unroll
    for (int k = 0; k < 5; k++) {
        unsigned xw = wds[3*k+0], yw = wds[3*k+1], zw = wds[3*k+2];
        acc[8*k+0] = fmaf(w, dec12(xw & 0xFFFu),                       acc[8*k+0]);
        acc[8*k+1] = fmaf(w, dec12((xw >> 12) & 0xFFFu),               acc[8*k+1]);
        acc[8*k+2] = fmaf(w, dec12(((xw >> 24) | (yw << 8)) & 0xFFFu), acc[8*k+2]);
        acc[8*k+3] = fmaf(w, dec12((yw >> 4) & 0xFFFu),                acc[8*k+3]);
        acc[8*k+4] = fmaf(w, dec12((yw >> 16) & 0xFFFu),               acc[8*k+4]);
        acc[8*k+5] = fmaf(w, dec12(((yw >> 28) | (zw << 4)) & 0xFFFu), acc[8*k+5]);
        acc[8*k+6] = fmaf(w, dec12((zw >> 8) & 0xFFFu),                acc[8*k+6]);
        acc[8*k+7] = fmaf(w, dec12((zw >> 20) & 0xFFFu),               acc[8*k+7]);
    }
}

// ---------------- fused aggregate + finalize (+ optional fused z2 emit) ----------------
// EMITZ: also compute z2 = relu(h @ w2 + b2) and write 12-bit packed zq2 (all nodes);
//        h rows written to outbuf only for node < nOut.
template <int RW, int TIN, int TOFF, bool EMITZ>
__global__ __launch_bounds__(256) void fin_kernel(
    const float* __restrict__ in,            // node features, stride RW (fp32)
    const unsigned* __restrict__ zq,         // N x 16 uints (12-bit packed z)
    const int* __restrict__ offsets,
    const ull* __restrict__ csr,             // [src:19 @32][w:32 @0]
    const float* __restrict__ wre, const float* __restrict__ bre,   // 64x32, 32
    const float* __restrict__ wrt, const float* __restrict__ brt,   // (TIN+8)x8, 8
    const float* __restrict__ w2e, const float* __restrict__ b2e,   // 32x32, 32 (EMITZ)
    const float* __restrict__ w2t, const float* __restrict__ b2t,   // 8x8, 8    (EMITZ)
    float* __restrict__ outbuf, int nOut,    // h rows for node < nOut, stride 40
    unsigned* __restrict__ zq2,              // EMITZ: n x 16 uints
    int n)
{
    __shared__ float sWe[64 * 32];
    __shared__ float sWt[(TIN + 8) * 8];
    __shared__ float sBe[32];
    __shared__ float sBt[8];
    __shared__ float sW2e[32 * 32];
    __shared__ float sW2t[8 * 8];
    __shared__ float sB2e[32];
    __shared__ float sB2t[8];
    for (int i = threadIdx.x; i < 64 * 32; i += 256) sWe[i] = wre[i];
    for (int i = threadIdx.x; i < (TIN + 8) * 8; i += 256) sWt[i] = wrt[i];
    if (threadIdx.x < 32) sBe[threadIdx.x] = bre[threadIdx.x];
    if (threadIdx.x < 8)  sBt[threadIdx.x] = brt[threadIdx.x];
    if (EMITZ) {
        for (int i = threadIdx.x; i < 32 * 32; i += 256) sW2e[i] = w2e[i];
        for (int i = threadIdx.x; i < 8 * 8; i += 256) sW2t[i] = w2t[i];
        if (threadIdx.x < 32) sB2e[threadIdx.x] = b2e[threadIdx.x];
        if (threadIdx.x < 8)  sB2t[threadIdx.x] = b2t[threadIdx.x];
    }
    __syncthreads();

    int node = blockIdx.x * 256 + threadIdx.x;
    if (node >= n) return;

    float acc[40];
    #pragma unroll
    for (int j = 0; j < 40; j++) acc[j] = 0.0f;
    float wsum = 1.0f;

    int e0 = offsets[node];
    int e1 = offsets[node + 1];
    int e = e0;
    // unroll-2: issue both edges' loads before consuming (MLP)
    for (; e + 2 <= e1; e += 2) {
        ull pk0 = csr[e];
        ull pk1 = csr[e + 1];
        const uint4* p0 = (const uint4*)(zq + (size_t)((pk0 >> 32) & 0x7FFFFull) * 16);
        const uint4* p1 = (const uint4*)(zq + (size_t)((pk1 >> 32) & 0x7FFFFull) * 16);
        uint4 A0 = p0[0], B0 = p0[1], C0 = p0[2], D0 = p0[3];
        uint4 A1 = p1[0], B1 = p1[1], C1 = p1[2], D1 = p1[3];
        float w0 = __uint_as_float((unsigned int)pk0);
        float w1 = __uint_as_float((unsigned int)pk1);
        acc_edge(acc, w0, A0, B0, C0, D0);
        acc_edge(acc, w1, A1, B1, C1, D1);
        wsum += w0;
        wsum += w1;
    }
    if (e < e1) {
        ull pk = csr[e];
        const uint4* zp = (const uint4*)(zq + (size_t)((pk >> 32) & 0x7FFFFull) * 16);
        uint4 A = zp[0], B = zp[1], C = zp[2], D = zp[3];
        float w = __uint_as_float((unsigned int)pk);
        acc_edge(acc, w, A, B, C, D);
        wsum += w;
    }
    float inv = 1.0f / wsum;
    #pragma unroll
    for (int j = 0; j < 40; j++) acc[j] *= inv;

    float row[RW];
    {
        const float4* rp = (const float4*)(in + (size_t)node * RW);
        #pragma unroll
        for (int q = 0; q < RW / 4; q++) {
            float4 v = rp[q];
            row[4*q] = v.x; row[4*q+1] = v.y; row[4*q+2] = v.z; row[4*q+3] = v.w;
        }
    }

    float h[40];

    // e-part: [row(0:32), aggE(32)] @ We(64x32) + be
    {
        float o[32];
        #pragma unroll
        for (int j = 0; j < 32; j++) o[j] = sBe[j];
        #pragma unroll
        for (int i = 0; i < 32; i++) {
            float v = row[i];
            #pragma unroll
            for (int j = 0; j < 32; j++) o[j] = fmaf(v, sWe[i * 32 + j], o[j]);
        }
        #pragma unroll
        for (int i = 0; i < 32; i++) {
            float v = acc[i];
            #pragma unroll
            for (int j = 0; j < 32; j++) o[j] = fmaf(v, sWe[(32 + i) * 32 + j], o[j]);
        }
        #pragma unroll
        for (int j = 0; j < 32; j++) h[j] = relu_(o[j]);
    }
    // t-part: [row(TOFF:TOFF+TIN), aggT(8)] @ Wt((TIN+8)x8) + bt
    {
        float ot[8];
        #pragma unroll
        for (int j = 0; j < 8; j++) ot[j] = sBt[j];
        #pragma unroll
        for (int i = 0; i < TIN; i++) {
            float v = row[TOFF + i];
            #pragma unroll
            for (int j = 0; j < 8; j++) ot[j] = fmaf(v, sWt[i * 8 + j], ot[j]);
        }
        #pragma unroll
        for (int i = 0; i < 8; i++) {
            float v = acc[32 + i];
            #pragma unroll
            for (int j = 0; j < 8; j++) ot[j] = fmaf(v, sWt[(TIN + i) * 8 + j], ot[j]);
        }
        #pragma unroll
        for (int j = 0; j < 8; j++) h[32 + j] = relu_(ot[j]);
    }

    if (node < nOut) {
        float4* ov = (float4*)(outbuf + (size_t)node * 40);
        #pragma unroll
        for (int q = 0; q < 10; q++)
            ov[q] = make_float4(h[4*q], h[4*q+1], h[4*q+2], h[4*q+3]);
    }

    if (EMITZ) {
        // z2 = relu(h[0:32] @ w2e + b2e) ++ relu(h[32:40] @ w2t + b2t) -> 12-bit pack
        float z2[40];
        #pragma unroll
        for (int j = 0; j < 32; j++) z2[j] = sB2e[j];
        #pragma unroll
        for (int i = 0; i < 32; i++) {
            float v = h[i];
            #pragma unroll
            for (int j = 0; j < 32; j++) z2[j] = fmaf(v, sW2e[i * 32 + j], z2[j]);
        }
        #pragma unroll
        for (int j = 0; j < 8; j++) z2[32 + j] = sB2t[j];
        #pragma unroll
        for (int i = 0; i < 8; i++) {
            float v = h[32 + i];
            #pragma unroll
            for (int j = 0; j < 8; j++) z2[32 + j] = fmaf(v, sW2t[i * 8 + j], z2[32 + j]);
        }
        unsigned b[40];
        #pragma unroll
        for (int i = 0; i < 40; i++) b[i] = enc12(relu_(z2[i]));
        unsigned wd[16];
        #pragma unroll
        for (int k = 0; k < 5; k++) {
            wd[3*k+0] = b[8*k+0] | (b[8*k+1] << 12) | (b[8*k+2] << 24);
            wd[3*k+1] = (b[8*k+2] >> 8) | (b[8*k+3] << 4) | (b[8*k+4] << 16) | (b[8*k+5] << 28);
            wd[3*k+2] = (b[8*k+5] >> 4) | (b[8*k+6] << 8) | (b[8*k+7] << 20);
        }
        wd[15] = 0;
        uint4* zv = (uint4*)(zq2 + (size_t)node * 16);
        #pragma unroll
        for (int q = 0; q < 4; q++)
            zv[q] = make_uint4(wd[4*q], wd[4*q+1], wd[4*q+2], wd[4*q+3]);
    }
}

// ---------------- loss ----------------

__device__ __forceinline__ void load40(const float* p, float* r) {
    const float4* v = (const float4*)p;
    #pragma unroll
    for (int q = 0; q < 10; q++) {
        float4 t = v[q];
        r[4*q] = t.x; r[4*q+1] = t.y; r[4*q+2] = t.z; r[4*q+3] = t.w;
    }
}

__device__ __forceinline__ float dot40(const float* a, const float* b) {
    float s = 0.0f;
    #pragma unroll
    for (int d = 0; d < 40; d++) s = fmaf(a[d], b[d], s);
    return s;
}

__device__ __forceinline__ void softmax5(const float l[5], float q[5]) {
    float m = l[0];
    #pragma unroll
    for (int c = 1; c < 5; c++) m = fmaxf(m, l[c]);
    float s = 0.0f;
    #pragma unroll
    for (int c = 0; c < 5; c++) { q[c] = expf(l[c] - m); s += q[c]; }
    float inv = 1.0f / s;
    #pragma unroll
    for (int c = 0; c < 5; c++) q[c] *= inv;
}

__device__ __forceinline__ float ent5(const float q[5]) {
    float e = 0.0f;
    #pragma unroll
    for (int c = 0; c < 5; c++) e += q[c] * logf(q[c] + 1e-20f);
    return e;
}

__device__ __forceinline__ float dot5(const float* a, const float* b) {
    float s = 0.0f;
    #pragma unroll
    for (int c = 0; c < 5; c++) s += a[c] * b[c];
    return s;
}

__global__ __launch_bounds__(256) void loss_kernel(
    const float* __restrict__ emb,       // BQ x 5 x 40
    const float* __restrict__ cent,      // 5 x 32
    const float* __restrict__ cent_t,    // 5 x 8
    float* __restrict__ out)
{
    __shared__ float sC[5 * 40];
    for (int i = threadIdx.x; i < 200; i += 256) {
        int c = i / 40, d = i % 40;
        sC[i] = (d < 32) ? cent[c * 32 + d] : cent_t[c * 8 + (d - 32)];
    }
    __syncthreads();

    int i = blockIdx.x * 256 + threadIdx.x;
    float contrib = 0.0f;
    if (i < BQ) {
        const float* base = emb + (size_t)i * 200;

        float ctr[40];
        load40(base, ctr);
        float l[5];
        #pragma unroll
        for (int c = 0; c < 5; c++) l[c] = dot40(ctr, sC + c * 40);
        float qc[5];
        softmax5(l, qc);
        float ent = ent5(qc);

        float rowv[40];
        load40(base + 40, rowv);
        float pd = dot40(ctr, rowv);
        #pragma unroll
        for (int c = 0; c < 5; c++) l[c] = dot40(rowv, sC + c * 40);
        float qp[5];
        softmax5(l, qp);
        float cpd = dot5(qc, qp);
        ent += ent5(qp);

        float nd = -1e30f, cnd = -1e30f;
        #pragma unroll
        for (int k = 0; k < 3; k++) {
            load40(base + (2 + k) * 40, rowv);
            nd = fmaxf(nd, dot40(ctr, rowv));
            #pragma unroll
            for (int c = 0; c < 5; c++) l[c] = dot40(rowv, sC + c * 40);
            float qn[5];
            softmax5(l, qn);
            cnd = fmaxf(cnd, dot5(qc, qn));
            ent += ent5(qn);
        }

        float mm  = fmaxf(nd - pd + 1.0f, 0.0f);
        float cmm = fmaxf(cnd - cpd + 1.0f, 0.0f);
        contrib = (mm + cmm) * (1.0f / (float)BQ) + 0.01f * (1.0f / (float)BS) * ent;
    }

    #pragma unroll
    for (int off = 32; off > 0; off >>= 1) contrib += __shfl_down(contrib, off);
    if ((threadIdx.x & 63) == 0) atomicAdd(out, contrib);
}

// ---------------- launch ----------------

extern "C" void kernel_launch(void* const* d_in, const int* in_sizes, int n_in,
                              void* d_out, int out_size, void* d_ws, size_t ws_size,
                              hipStream_t stream) {
    const float* x      = (const float*)d_in[0];
    const float* weight = (const float*)d_in[1];
    const float* e_w1l  = (const float*)d_in[2];
    const float* e_b1l  = (const float*)d_in[3];
    const float* e_w1r  = (const float*)d_in[4];
    const float* e_b1r  = (const float*)d_in[5];
    const float* e_w2l  = (const float*)d_in[6];
    const float* e_b2l  = (const float*)d_in[7];
    const float* e_w2r  = (const float*)d_in[8];
    const float* e_b2r  = (const float*)d_in[9];
    const float* t_w1l  = (const float*)d_in[10];
    const float* t_b1l  = (const float*)d_in[11];
    const float* t_w1r  = (const float*)d_in[12];
    const float* t_b1r  = (const float*)d_in[13];
    const float* t_w2l  = (const float*)d_in[14];
    const float* t_b2l  = (const float*)d_in[15];
    const float* t_w2r  = (const float*)d_in[16];
    const float* t_b2r  = (const float*)d_in[17];
    const float* cent   = (const float*)d_in[18];
    const float* cent_t = (const float*)d_in[19];
    const int*   eidx   = (const int*)d_in[20];

    const int E = in_sizes[20] / 2;
    const int N = in_sizes[0] / 32;
    const int* srcI = eidx;
    const int* dstI = eidx + E;
    float* out = (float*)d_out;

    const int NC = (N + CB - 1) / CB;    // 245 coarse buckets (2048 nodes)

    char* p = (char*)d_ws;
    auto alloc = [&](size_t bytes) -> char* {
        char* r = p;
        p += (bytes + 255) & ~(size_t)255;
        return r;
    };
    // region A: tmp (64 MB) aliased with zq1 (32 MB) — disjoint lifetimes
    char* regionA = alloc((size_t)E * 8);
    ull*  tmp     = (ull*)regionA;
    unsigned* zq1 = (unsigned*)regionA;
    unsigned* zq2 = (unsigned*)alloc((size_t)N * 64);         // 32 MB
    float* hcat   = (float*)alloc((size_t)BS * 40 * 4);       // 16 MB (only BS rows needed)
    float* emb    = (float*)alloc((size_t)BS * 40 * 4);       // 16 MB
    ull*   csr    = (ull*)alloc((size_t)E * 8);               // 64 MB
    int*   offsets= (int*)alloc((size_t)(N + 1) * 4);
    int*   hist2D = (int*)alloc((size_t)NC * NWG * 4);        // 0.5 MB
    int*   wgbase = (int*)alloc((size_t)NC * NWG * 4);        // 0.5 MB
    int*   bucketTot  = (int*)alloc((size_t)NC * 4);
    int*   bucketBase = (int*)alloc((size_t)NC * 4);
    (void)ws_size;

    hipMemsetAsync(d_out, 0, sizeof(float), stream);

    // binning
    hist_kernel<<<NWG, 256, 0, stream>>>(dstI, E, NC, hist2D);
    reduce_kernel<<<NC, 256, 0, stream>>>(hist2D, bucketTot);
    scanTot_kernel<<<1, 256, 0, stream>>>(bucketTot, NC, bucketBase);
    scanB_kernel<<<NC, NWG, 0, stream>>>(hist2D, bucketBase, wgbase);
    fillA_kernel<<<NWG, 256, 0, stream>>>(srcI, dstI, weight, E, NC, wgbase, tmp);
    fillA2B_kernel<<<NC, 512, 0, stream>>>(tmp, wgbase, NC, N, E, csr, offsets);

    const int nb = (N + 255) / 256;
    // layer 1 z (x -> zq1)
    z1_kernel<<<nb, 256, 0, stream>>>(x, e_w1l, e_b1l, t_w1l, t_b1l, zq1, N);
    // fused: layer-1 fin + layer-2 z  (writes hcat[<BS] and zq2[all N])
    fin_kernel<32, 32, 0, true><<<nb, 256, 0, stream>>>(
        x, zq1, offsets, csr,
        e_w1r, e_b1r, t_w1r, t_b1r,
        e_w2l, e_b2l, t_w2l, t_b2l,
        hcat, BS, zq2, N);
    // layer-2 fin (only BS nodes)
    const int nb2 = (BS + 255) / 256;
    fin_kernel<40, 8, 32, false><<<nb2, 256, 0, stream>>>(
        hcat, zq2, offsets, csr,
        e_w2r, e_b2r, t_w2r, t_b2r,
        nullptr, nullptr, nullptr, nullptr,
        emb, BS, nullptr, BS);

    loss_kernel<<<(BQ + 255) / 256, 256, 0, stream>>>(emb, cent, cent_t, out);
}

// Round 12
// 579.752 us; speedup vs baseline: 1.9892x; 1.1251x over previous
//
#include <hip/hip_runtime.h>

#define BS 100000
#define BQ 20000          // BS / 5
#define NWG 512           // workgroups in hist/fillA partition
#define CB  2048          // nodes per coarse bucket
#define NCMAX 256

typedef unsigned long long ull;

__device__ __forceinline__ float relu_(float v) { return fmaxf(v, 0.0f); }

// ---- 12-bit unsigned float codec (e5|m7, bias 112) ----
__device__ __forceinline__ unsigned enc12(float f) {
    unsigned u = __float_as_uint(f);
    if (u < 0x38000000u) return 0u;
    unsigned r = u - 0x38000000u;
    unsigned b = (r + 0x7FFFu + ((r >> 16) & 1u)) >> 16;
    return (b > 0xFFFu) ? 0xFFFu : b;
}
__device__ __forceinline__ float dec12(unsigned b) {
    return __uint_as_float((b << 16) + 0x38000000u);
}

// ================= binning =================
// tmp record: [dst&2047:11 @51][src:19 @32][wbits:32 @0]
// csr record (4 B): [src:19 @13][w_fix13 @0]   w ~= wq/8191
// hist2D layout: [bucket][wg]

__global__ __launch_bounds__(256) void hist_kernel(
    const int* __restrict__ dst, int E, int NC, int per, int* __restrict__ hist2D)
{
    __shared__ int lc[NCMAX];
    int t = threadIdx.x, g = blockIdx.x;
    for (int i = t; i < NC; i += 256) lc[i] = 0;
    __syncthreads();
    int lo = g * per, hi = min(lo + per, E);
    if (lo < hi) {
        int nq = (hi - lo) >> 2;
        const int4* dst4 = (const int4*)(dst + lo);
        for (int q = t; q < nq; q += 256) {
            int4 d = dst4[q];
            atomicAdd(&lc[d.x >> 11], 1);
            atomicAdd(&lc[d.y >> 11], 1);
            atomicAdd(&lc[d.z >> 11], 1);
            atomicAdd(&lc[d.w >> 11], 1);
        }
        for (int i = lo + (nq << 2) + t; i < hi; i += 256)
            atomicAdd(&lc[dst[i] >> 11], 1);
    }
    __syncthreads();
    for (int b = t; b < NC; b += 256) hist2D[b * NWG + g] = lc[b];
}

__global__ __launch_bounds__(256) void reduce_kernel(
    const int* __restrict__ hist2D, int* __restrict__ bucketTot)
{
    __shared__ int s[256];
    int b = blockIdx.x, t = threadIdx.x;
    int sum = 0;
    for (int g = t; g < NWG; g += 256) sum += hist2D[(size_t)b * NWG + g];
    s[t] = sum;
    __syncthreads();
    for (int d = 128; d > 0; d >>= 1) {
        if (t < d) s[t] += s[t + d];
        __syncthreads();
    }
    if (t == 0) bucketTot[b] = s[0];
}

__global__ __launch_bounds__(256) void scanTot_kernel(
    const int* __restrict__ bucketTot, int NC, int* __restrict__ bucketBase)
{
    __shared__ int s[256];
    int t = threadIdx.x;
    int v = (t < NC) ? bucketTot[t] : 0;
    s[t] = v;
    __syncthreads();
    for (int d = 1; d < 256; d <<= 1) {
        int x = (t >= d) ? s[t - d] : 0;
        __syncthreads();
        s[t] += x;
        __syncthreads();
    }
    if (t < NC) bucketBase[t] = s[t] - v;
}

__global__ __launch_bounds__(NWG) void scanB_kernel(
    const int* __restrict__ hist2D, const int* __restrict__ bucketBase,
    int* __restrict__ wgbase)
{
    __shared__ int s[NWG];
    int b = blockIdx.x, g = threadIdx.x;
    int v = hist2D[(size_t)b * NWG + g];
    s[g] = v;
    __syncthreads();
    for (int d = 1; d < NWG; d <<= 1) {
        int x = (g >= d) ? s[g - d] : 0;
        __syncthreads();
        s[g] += x;
        __syncthreads();
    }
    wgbase[(size_t)b * NWG + g] = bucketBase[b] + s[g] - v;
}

__device__ __forceinline__ void fillA_one(int d, int s, float wv,
    int* cur, ull* __restrict__ tmp)
{
    int b = d >> 11;
    int pos = atomicAdd(&cur[b], 1);
    ull rec = (ull)__float_as_uint(wv)
            | ((ull)(unsigned int)s << 32)
            | ((ull)(unsigned int)(d & (CB - 1)) << 51);
    tmp[pos] = rec;
}

__global__ __launch_bounds__(256) void fillA_kernel(
    const int* __restrict__ src, const int* __restrict__ dst,
    const float* __restrict__ w, int E, int NC, int per,
    const int* __restrict__ wgbase, ull* __restrict__ tmp)
{
    __shared__ int cur[NCMAX];
    int t = threadIdx.x, g = blockIdx.x;
    for (int i = t; i < NC; i += 256) cur[i] = wgbase[(size_t)i * NWG + g];
    __syncthreads();
    int lo = g * per, hi = min(lo + per, E);
    if (lo >= hi) return;
    int nq = (hi - lo) >> 2;
    const int4* src4 = (const int4*)(src + lo);
    const int4* dst4 = (const int4*)(dst + lo);
    const float4* w4 = (const float4*)(w + lo);
    for (int q = t; q < nq; q += 256) {
        int4 d = dst4[q];
        int4 s = src4[q];
        float4 wv = w4[q];
        fillA_one(d.x, s.x, wv.x, cur, tmp);
        fillA_one(d.y, s.y, wv.y, cur, tmp);
        fillA_one(d.z, s.z, wv.z, cur, tmp);
        fillA_one(d.w, s.w, wv.w, cur, tmp);
    }
    for (int i = lo + (nq << 2) + t; i < hi; i += 256)
        fillA_one(dst[i], src[i], w[i], cur, tmp);
}

// one WG (512 thr) per coarse bucket: count -> scan(2048) -> 4-B csr scatter
__global__ __launch_bounds__(512) void fillA2B_kernel(
    const ull* __restrict__ tmp, const int* __restrict__ wgbase,
    int NC, int N, int E,
    unsigned* __restrict__ csr, int* __restrict__ offsets)
{
    __shared__ int cnt[CB];
    __shared__ int ssum[512];
    int b = blockIdx.x, t = threadIdx.x;
    int lo = wgbase[(size_t)b * NWG];
    int hi = (b == NC - 1) ? E : wgbase[(size_t)(b + 1) * NWG];
    int M = hi - lo;

    #pragma unroll
    for (int k = 0; k < CB / 512; k++) cnt[t + k * 512] = 0;
    __syncthreads();
    {
        int k = t;
        for (; k + 512 < M; k += 1024) {
            ull r0 = tmp[lo + k];
            ull r1 = tmp[lo + k + 512];
            atomicAdd(&cnt[(int)(r0 >> 51)], 1);
            atomicAdd(&cnt[(int)(r1 >> 51)], 1);
        }
        if (k < M) atomicAdd(&cnt[(int)(tmp[lo + k] >> 51)], 1);
    }
    __syncthreads();

    int base = t * 4;
    int loc[4];
    int run = 0;
    #pragma unroll
    for (int k = 0; k < 4; k++) { loc[k] = run; run += cnt[base + k]; }
    ssum[t] = run;
    __syncthreads();
    for (int d = 1; d < 512; d <<= 1) {
        int x = (t >= d) ? ssum[t - d] : 0;
        __syncthreads();
        ssum[t] += x;
        __syncthreads();
    }
    int excl = ssum[t] - run;

    int nodeBase = b * CB;
    #pragma unroll
    for (int k = 0; k < 4; k++) {
        int node = nodeBase + base + k;
        if (node < N) offsets[node] = lo + excl + loc[k];
        loc[k] += excl;
    }
    if (b == NC - 1 && t == 0) offsets[N] = E;
    __syncthreads();
    #pragma unroll
    for (int k = 0; k < 4; k++) cnt[base + k] = loc[k];
    __syncthreads();

    for (int e = lo + t; e < hi; e += 512) {
        ull rec = tmp[e];
        int dl = (int)(rec >> 51);
        int pos = atomicAdd(&cnt[dl], 1);
        float w = __uint_as_float((unsigned int)(rec & 0xFFFFFFFFull));
        unsigned wq = (unsigned)fmaf(w, 8191.0f, 0.5f);   // w in [0,1)
        unsigned sidx = (unsigned)((rec >> 32) & 0x7FFFFull);
        csr[lo + pos] = (sidx << 13) | wq;
    }
}

// ---------------- z1 = relu(x @ Wl + bl) -> 12-bit packed rows ----------------
__global__ __launch_bounds__(256) void z1_kernel(
    const float* __restrict__ in,
    const float* __restrict__ we, const float* __restrict__ be,
    const float* __restrict__ wt, const float* __restrict__ bt,
    unsigned* __restrict__ zq, int n)
{
    __shared__ float sWe[32 * 32];
    __shared__ float sWt[32 * 8];
    __shared__ float sBe[32];
    __shared__ float sBt[8];
    for (int i = threadIdx.x; i < 32 * 32; i += 256) sWe[i] = we[i];
    for (int i = threadIdx.x; i < 32 * 8; i += 256) sWt[i] = wt[i];
    if (threadIdx.x < 32) sBe[threadIdx.x] = be[threadIdx.x];
    if (threadIdx.x < 8)  sBt[threadIdx.x] = bt[threadIdx.x];
    __syncthreads();

    int node = blockIdx.x * 256 + threadIdx.x;
    if (node >= n) return;

    float row[32];
    {
        const float4* rp = (const float4*)(in + (size_t)node * 32);
        #pragma unroll
        for (int q = 0; q < 8; q++) {
            float4 v = rp[q];
            row[4*q] = v.x; row[4*q+1] = v.y; row[4*q+2] = v.z; row[4*q+3] = v.w;
        }
    }

    float o[40];
    #pragma unroll
    for (int j = 0; j < 32; j++) o[j] = sBe[j];
    #pragma unroll
    for (int i = 0; i < 32; i++) {
        float v = row[i];
        #pragma unroll
        for (int j = 0; j < 32; j++) o[j] = fmaf(v, sWe[i * 32 + j], o[j]);
    }
    #pragma unroll
    for (int j = 0; j < 8; j++) o[32 + j] = sBt[j];
    #pragma unroll
    for (int i = 0; i < 32; i++) {
        float v = row[i];
        #pragma unroll
        for (int j = 0; j < 8; j++) o[32 + j] = fmaf(v, sWt[i * 8 + j], o[32 + j]);
    }

    unsigned b[40];
    #pragma unroll
    for (int i = 0; i < 40; i++) b[i] = enc12(relu_(o[i]));
    unsigned wd[16];
    #pragma unroll
    for (int k = 0; k < 5; k++) {
        wd[3*k+0] = b[8*k+0] | (b[8*k+1] << 12) | (b[8*k+2] << 24);
        wd[3*k+1] = (b[8*k+2] >> 8) | (b[8*k+3] << 4) | (b[8*k+4] << 16) | (b[8*k+5] << 28);
        wd[3*k+2] = (b[8*k+5] >> 4) | (b[8*k+6] << 8) | (b[8*k+7] << 20);
    }
    wd[15] = 0;
    uint4* zv = (uint4*)(zq + (size_t)node * 16);
    #pragma unroll
    for (int q = 0; q < 4; q++)
        zv[q] = make_uint4(wd[4*q], wd[4*q+1], wd[4*q+2], wd[4*q+3]);
}

// ---------------- decode+accumulate one edge ----------------
__device__ __forceinline__ void acc_edge(float* acc, float w,
    const uint4& A, const uint4& B, const uint4& C, const uint4& D)
{
    unsigned wds[15] = {A.x, A.y, A.z, A.w, B.x, B.y, B.z, B.w,
                        C.x, C.y, C.z, C.w, D.x, D.y, D.z};
    #pragma unroll
    for (int k = 0; k < 5; k++) {
        unsigned xw = wds[3*k+0], yw = wds[3*k+1], zw = wds[3*k+2];
        acc[8*k+0] = fmaf(w, dec12(xw & 0xFFFu),                       acc[8*k+0]);
        acc[8*k+1] = fmaf(w, dec12((xw >> 12) & 0xFFFu),               acc[8*k+1]);
        acc[8*k+2] = fmaf(w, dec12(((xw >> 24) | (yw << 8)) & 0xFFFu), acc[8*k+2]);
        acc[8*k+3] = fmaf(w, dec12((yw >> 4) & 0xFFFu),                acc[8*k+3]);
        acc[8*k+4] = fmaf(w, dec12((yw >> 16) & 0xFFFu),               acc[8*k+4]);
        acc[8*k+5] = fmaf(w, dec12(((yw >> 28) | (zw << 4)) & 0xFFFu), acc[8*k+5]);
        acc[8*k+6] = fmaf(w, dec12((zw >> 8) & 0xFFFu),                acc[8*k+6]);
        acc[8*k+7] = fmaf(w, dec12((zw >> 20) & 0xFFFu),               acc[8*k+7]);
    }
}

// ---------------- fused aggregate + finalize (+ optional fused z2 emit) ----------------
template <int RW, int TIN, int TOFF, bool EMITZ>
__global__ __launch_bounds__(256) void fin_kernel(
    const float* __restrict__ in,
    const unsigned* __restrict__ zq,
    const int* __restrict__ offsets,
    const unsigned* __restrict__ csr,        // 4-B records [src:19 @13][w13 @0]
    const float* __restrict__ wre, const float* __restrict__ bre,
    const float* __restrict__ wrt, const float* __restrict__ brt,
    const float* __restrict__ w2e, const float* __restrict__ b2e,
    const float* __restrict__ w2t, const float* __restrict__ b2t,
    float* __restrict__ outbuf, int nOut,
    unsigned* __restrict__ zq2,
    int n)
{
    __shared__ float sWe[64 * 32];
    __shared__ float sWt[(TIN + 8) * 8];
    __shared__ float sBe[32];
    __shared__ float sBt[8];
    __shared__ float sW2e[32 * 32];
    __shared__ float sW2t[8 * 8];
    __shared__ float sB2e[32];
    __shared__ float sB2t[8];
    for (int i = threadIdx.x; i < 64 * 32; i += 256) sWe[i] = wre[i];
    for (int i = threadIdx.x; i < (TIN + 8) * 8; i += 256) sWt[i] = wrt[i];
    if (threadIdx.x < 32) sBe[threadIdx.x] = bre[threadIdx.x];
    if (threadIdx.x < 8)  sBt[threadIdx.x] = brt[threadIdx.x];
    if (EMITZ) {
        for (int i = threadIdx.x; i < 32 * 32; i += 256) sW2e[i] = w2e[i];
        for (int i = threadIdx.x; i < 8 * 8; i += 256) sW2t[i] = w2t[i];
        if (threadIdx.x < 32) sB2e[threadIdx.x] = b2e[threadIdx.x];
        if (threadIdx.x < 8)  sB2t[threadIdx.x] = b2t[threadIdx.x];
    }
    __syncthreads();

    int node = blockIdx.x * 256 + threadIdx.x;
    if (node >= n) return;

    float acc[40];
    #pragma unroll
    for (int j = 0; j < 40; j++) acc[j] = 0.0f;
    float wsum = 1.0f;

    const float DW = 1.0f / 8191.0f;
    int e0 = offsets[node];
    int e1 = offsets[node + 1];
    int e = e0;
    for (; e + 2 <= e1; e += 2) {
        unsigned pk0 = csr[e];
        unsigned pk1 = csr[e + 1];
        const uint4* p0 = (const uint4*)(zq + (size_t)(pk0 >> 13) * 16);
        const uint4* p1 = (const uint4*)(zq + (size_t)(pk1 >> 13) * 16);
        uint4 A0 = p0[0], B0 = p0[1], C0 = p0[2], D0 = p0[3];
        uint4 A1 = p1[0], B1 = p1[1], C1 = p1[2], D1 = p1[3];
        float w0 = (float)(pk0 & 8191u) * DW;
        float w1 = (float)(pk1 & 8191u) * DW;
        acc_edge(acc, w0, A0, B0, C0, D0);
        acc_edge(acc, w1, A1, B1, C1, D1);
        wsum += w0;
        wsum += w1;
    }
    if (e < e1) {
        unsigned pk = csr[e];
        const uint4* zp = (const uint4*)(zq + (size_t)(pk >> 13) * 16);
        uint4 A = zp[0], B = zp[1], C = zp[2], D = zp[3];
        float w = (float)(pk & 8191u) * DW;
        acc_edge(acc, w, A, B, C, D);
        wsum += w;
    }
    float inv = 1.0f / wsum;
    #pragma unroll
    for (int j = 0; j < 40; j++) acc[j] *= inv;

    float row[RW];
    {
        const float4* rp = (const float4*)(in + (size_t)node * RW);
        #pragma unroll
        for (int q = 0; q < RW / 4; q++) {
            float4 v = rp[q];
            row[4*q] = v.x; row[4*q+1] = v.y; row[4*q+2] = v.z; row[4*q+3] = v.w;
        }
    }

    float h[40];

    {
        float o[32];
        #pragma unroll
        for (int j = 0; j < 32; j++) o[j] = sBe[j];
        #pragma unroll
        for (int i = 0; i < 32; i++) {
            float v = row[i];
            #pragma unroll
            for (int j = 0; j < 32; j++) o[j] = fmaf(v, sWe[i * 32 + j], o[j]);
        }
        #pragma unroll
        for (int i = 0; i < 32; i++) {
            float v = acc[i];
            #pragma unroll
            for (int j = 0; j < 32; j++) o[j] = fmaf(v, sWe[(32 + i) * 32 + j], o[j]);
        }
        #pragma unroll
        for (int j = 0; j < 32; j++) h[j] = relu_(o[j]);
    }
    {
        float ot[8];
        #pragma unroll
        for (int j = 0; j < 8; j++) ot[j] = sBt[j];
        #pragma unroll
        for (int i = 0; i < TIN; i++) {
            float v = row[TOFF + i];
            #pragma unroll
            for (int j = 0; j < 8; j++) ot[j] = fmaf(v, sWt[i * 8 + j], ot[j]);
        }
        #pragma unroll
        for (int i = 0; i < 8; i++) {
            float v = acc[32 + i];
            #pragma unroll
            for (int j = 0; j < 8; j++) ot[j] = fmaf(v, sWt[(TIN + i) * 8 + j], ot[j]);
        }
        #pragma unroll
        for (int j = 0; j < 8; j++) h[32 + j] = relu_(ot[j]);
    }

    if (node < nOut) {
        float4* ov = (float4*)(outbuf + (size_t)node * 40);
        #pragma unroll
        for (int q = 0; q < 10; q++)
            ov[q] = make_float4(h[4*q], h[4*q+1], h[4*q+2], h[4*q+3]);
    }

    if (EMITZ) {
        float z2[40];
        #pragma unroll
        for (int j = 0; j < 32; j++) z2[j] = sB2e[j];
        #pragma unroll
        for (int i = 0; i < 32; i++) {
            float v = h[i];
            #pragma unroll
            for (int j = 0; j < 32; j++) z2[j] = fmaf(v, sW2e[i * 32 + j], z2[j]);
        }
        #pragma unroll
        for (int j = 0; j < 8; j++) z2[32 + j] = sB2t[j];
        #pragma unroll
        for (int i = 0; i < 8; i++) {
            float v = h[32 + i];
            #pragma unroll
            for (int j = 0; j < 8; j++) z2[32 + j] = fmaf(v, sW2t[i * 8 + j], z2[32 + j]);
        }
        unsigned b[40];
        #pragma unroll
        for (int i = 0; i < 40; i++) b[i] = enc12(relu_(z2[i]));
        unsigned wd[16];
        #pragma unroll
        for (int k = 0; k < 5; k++) {
            wd[3*k+0] = b[8*k+0] | (b[8*k+1] << 12) | (b[8*k+2] << 24);
            wd[3*k+1] = (b[8*k+2] >> 8) | (b[8*k+3] << 4) | (b[8*k+4] << 16) | (b[8*k+5] << 28);
            wd[3*k+2] = (b[8*k+5] >> 4) | (b[8*k+6] << 8) | (b[8*k+7] << 20);
        }
        wd[15] = 0;
        uint4* zv = (uint4*)(zq2 + (size_t)node * 16);
        #pragma unroll
        for (int q = 0; q < 4; q++)
            zv[q] = make_uint4(wd[4*q], wd[4*q+1], wd[4*q+2], wd[4*q+3]);
    }
}

// ---------------- loss ----------------

__device__ __forceinline__ void load40(const float* p, float* r) {
    const float4* v = (const float4*)p;
    #pragma unroll
    for (int q = 0; q < 10; q++) {
        float4 t = v[q];
        r[4*q] = t.x; r[4*q+1] = t.y; r[4*q+2] = t.z; r[4*q+3] = t.w;
    }
}

__device__ __forceinline__ float dot40(const float* a, const float* b) {
    float s = 0.0f;
    #pragma unroll
    for (int d = 0; d < 40; d++) s = fmaf(a[d], b[d], s);
    return s;
}

__device__ __forceinline__ void softmax5(const float l[5], float q[5]) {
    float m = l[0];
    #pragma unroll
    for (int c = 1; c < 5; c++) m = fmaxf(m, l[c]);
    float s = 0.0f;
    #pragma unroll
    for (int c = 0; c < 5; c++) { q[c] = expf(l[c] - m); s += q[c]; }
    float inv = 1.0f / s;
    #pragma unroll
    for (int c = 0; c < 5; c++) q[c] *= inv;
}

__device__ __forceinline__ float ent5(const float q[5]) {
    float e = 0.0f;
    #pragma unroll
    for (int c = 0; c < 5; c++) e += q[c] * logf(q[c] + 1e-20f);
    return e;
}

__device__ __forceinline__ float dot5(const float* a, const float* b) {
    float s = 0.0f;
    #pragma unroll
    for (int c = 0; c < 5; c++) s += a[c] * b[c];
    return s;
}

__global__ __launch_bounds__(256) void loss_kernel(
    const float* __restrict__ emb,
    const float* __restrict__ cent,
    const float* __restrict__ cent_t,
    float* __restrict__ out)
{
    __shared__ float sC[5 * 40];
    for (int i = threadIdx.x; i < 200; i += 256) {
        int c = i / 40, d = i % 40;
        sC[i] = (d < 32) ? cent[c * 32 + d] : cent_t[c * 8 + (d - 32)];
    }
    __syncthreads();

    int i = blockIdx.x * 256 + threadIdx.x;
    float contrib = 0.0f;
    if (i < BQ) {
        const float* base = emb + (size_t)i * 200;

        float ctr[40];
        load40(base, ctr);
        float l[5];
        #pragma unroll
        for (int c = 0; c < 5; c++) l[c] = dot40(ctr, sC + c * 40);
        float qc[5];
        softmax5(l, qc);
        float ent = ent5(qc);

        float rowv[40];
        load40(base + 40, rowv);
        float pd = dot40(ctr, rowv);
        #pragma unroll
        for (int c = 0; c < 5; c++) l[c] = dot40(rowv, sC + c * 40);
        float qp[5];
        softmax5(l, qp);
        float cpd = dot5(qc, qp);
        ent += ent5(qp);

        float nd = -1e30f, cnd = -1e30f;
        #pragma unroll
        for (int k = 0; k < 3; k++) {
            load40(base + (2 + k) * 40, rowv);
            nd = fmaxf(nd, dot40(ctr, rowv));
            #pragma unroll
            for (int c = 0; c < 5; c++) l[c] = dot40(rowv, sC + c * 40);
            float qn[5];
            softmax5(l, qn);
            cnd = fmaxf(cnd, dot5(qc, qn));
            ent += ent5(qn);
        }

        float mm  = fmaxf(nd - pd + 1.0f, 0.0f);
        float cmm = fmaxf(cnd - cpd + 1.0f, 0.0f);
        contrib = (mm + cmm) * (1.0f / (float)BQ) + 0.01f * (1.0f / (float)BS) * ent;
    }

    #pragma unroll
    for (int off = 32; off > 0; off >>= 1) contrib += __shfl_down(contrib, off);
    if ((threadIdx.x & 63) == 0) atomicAdd(out, contrib);
}

// ---------------- launch ----------------

extern "C" void kernel_launch(void* const* d_in, const int* in_sizes, int n_in,
                              void* d_out, int out_size, void* d_ws, size_t ws_size,
                              hipStream_t stream) {
    const float* x      = (const float*)d_in[0];
    const float* weight = (const float*)d_in[1];
    const float* e_w1l  = (const float*)d_in[2];
    const float* e_b1l  = (const float*)d_in[3];
    const float* e_w1r  = (const float*)d_in[4];
    const float* e_b1r  = (const float*)d_in[5];
    const float* e_w2l  = (const float*)d_in[6];
    const float* e_b2l  = (const float*)d_in[7];
    const float* e_w2r  = (const float*)d_in[8];
    const float* e_b2r  = (const float*)d_in[9];
    const float* t_w1l  = (const float*)d_in[10];
    const float* t_b1l  = (const float*)d_in[11];
    const float* t_w1r  = (const float*)d_in[12];
    const float* t_b1r  = (const float*)d_in[13];
    const float* t_w2l  = (const float*)d_in[14];
    const float* t_b2l  = (const float*)d_in[15];
    const float* t_w2r  = (const float*)d_in[16];
    const float* t_b2r  = (const float*)d_in[17];
    const float* cent   = (const float*)d_in[18];
    const float* cent_t = (const float*)d_in[19];
    const int*   eidx   = (const int*)d_in[20];

    const int E = in_sizes[20] / 2;
    const int N = in_sizes[0] / 32;
    const int* srcI = eidx;
    const int* dstI = eidx + E;
    float* out = (float*)d_out;

    const int NC = (N + CB - 1) / CB;                    // 245 coarse buckets
    const int per = (((E + NWG - 1) / NWG) + 3) & ~3;    // WG slice, multiple of 4

    char* p = (char*)d_ws;
    auto alloc = [&](size_t bytes) -> char* {
        char* r = p;
        p += (bytes + 255) & ~(size_t)255;
        return r;
    };
    char* regionA = alloc((size_t)E * 8);                // tmp (64 MB) / zq1 (32 MB)
    ull*  tmp     = (ull*)regionA;
    unsigned* zq1 = (unsigned*)regionA;
    unsigned* zq2 = (unsigned*)alloc((size_t)N * 64);    // 32 MB
    float* hcat   = (float*)alloc((size_t)BS * 40 * 4);  // 16 MB
    float* emb    = (float*)alloc((size_t)BS * 40 * 4);  // 16 MB
    unsigned* csr = (unsigned*)alloc((size_t)E * 4);     // 32 MB (4-B records)
    int*   offsets= (int*)alloc((size_t)(N + 1) * 4);
    int*   hist2D = (int*)alloc((size_t)NC * NWG * 4);
    int*   wgbase = (int*)alloc((size_t)NC * NWG * 4);
    int*   bucketTot  = (int*)alloc((size_t)NC * 4);
    int*   bucketBase = (int*)alloc((size_t)NC * 4);
    (void)ws_size;

    hipMemsetAsync(d_out, 0, sizeof(float), stream);

    // binning
    hist_kernel<<<NWG, 256, 0, stream>>>(dstI, E, NC, per, hist2D);
    reduce_kernel<<<NC, 256, 0, stream>>>(hist2D, bucketTot);
    scanTot_kernel<<<1, 256, 0, stream>>>(bucketTot, NC, bucketBase);
    scanB_kernel<<<NC, NWG, 0, stream>>>(hist2D, bucketBase, wgbase);
    fillA_kernel<<<NWG, 256, 0, stream>>>(srcI, dstI, weight, E, NC, per, wgbase, tmp);
    fillA2B_kernel<<<NC, 512, 0, stream>>>(tmp, wgbase, NC, N, E, csr, offsets);

    const int nb = (N + 255) / 256;
    z1_kernel<<<nb, 256, 0, stream>>>(x, e_w1l, e_b1l, t_w1l, t_b1l, zq1, N);
    fin_kernel<32, 32, 0, true><<<nb, 256, 0, stream>>>(
        x, zq1, offsets, csr,
        e_w1r, e_b1r, t_w1r, t_b1r,
        e_w2l, e_b2l, t_w2l, t_b2l,
        hcat, BS, zq2, N);
    const int nb2 = (BS + 255) / 256;
    fin_kernel<40, 8, 32, false><<<nb2, 256, 0, stream>>>(
        hcat, zq2, offsets, csr,
        e_w2r, e_b2r, t_w2r, t_b2r,
        nullptr, nullptr, nullptr, nullptr,
        emb, BS, nullptr, BS);

    loss_kernel<<<(BQ + 255) / 256, 256, 0, stream>>>(emb, cent, cent_t, out);
}